// Round 2
// baseline (1005.553 us; speedup 1.0000x reference)
//
#include <hip/hip_runtime.h>
#include <hip/hip_bf16.h>
#include <math.h>

// GlobalSceneTokenizer fused pipeline, f32 in/out.
// R16: wave-local pipeline. Each wave owns 16 rows x ALL 256 channels
// (acc[16] f32x4 = 64 regs, same budget as the old 64x64 quadrant). LN stats
// are wave-local (in-register nt-sum + DPP rowsum16) -> ZERO barriers between
// the staging barrier and the P6 handshake. Stage1->gelu->stage2 round-trips
// through a per-wave 16-row LDS slab (a1s stride 200 / h1s stride 264 union,
// 8 x 4224 shorts = 67584 B, same total as R15); same-wave DS ops are
// in-order so no sync needed. Waves run desynchronized through the heavy
// region -> MFMA/VALU/VMEM latency hides across waves instead of
// convergence-stalling at 6 mid-kernel barriers + 2 LDS LN round-trips.
// Stage-2 k-permutation is now the involution pi(ch)=(ch&15)*16+(ch>>4) so a
// lane's 16 gelu outputs pack into one contiguous 32B LDS write; w2T prep
// permuted to match. Per-channel max -> LDS pool_s (atomicMax, no barrier),
// flushed to global at the P6 barrier (global atomics halved).
// a1s col map: [0..63]=pf | [64..66]=relxyz | [67..90]=relemb24 | [91]=0 |
//              [92..187]=absemb96 | [188..191]=0   (w1T rows remapped to match)

#define LN_EPS 1e-5f

typedef __attribute__((ext_vector_type(8))) short bf16x8;
typedef __attribute__((ext_vector_type(4))) float f32x4;
typedef __attribute__((ext_vector_type(2))) unsigned int u32x2;
typedef __attribute__((ext_vector_type(4))) unsigned int u32x4;

#if __has_builtin(__builtin_amdgcn_rcpf)
#define FRCP(x) __builtin_amdgcn_rcpf(x)
#else
#define FRCP(x) (1.0f / (x))
#endif

__device__ __forceinline__ unsigned short f2bf(float f) {
    unsigned int x = __float_as_uint(f);
    return (unsigned short)((x + 0x7FFFu + ((x >> 16) & 1u)) >> 16);  // RNE
}
__device__ __forceinline__ unsigned int pack2(float a, float b) {
    union { __hip_bfloat162 h; unsigned int u; } cvt;
    cvt.h = __float22bfloat162_rn(make_float2(a, b));
    return cvt.u;
}
__device__ __forceinline__ unsigned int fenc(float f) {
    unsigned int u = __float_as_uint(f);
    return (u & 0x80000000u) ? ~u : (u | 0x80000000u);
}
__device__ __forceinline__ float fdec(unsigned int u) {
    return __uint_as_float((u & 0x80000000u) ? (u & 0x7FFFFFFFu) : ~u);
}
__device__ __forceinline__ float gelu_fast(float x) {
    float x2 = x * x;
    float u = x * fmaf(0.0356774081f, x2, 0.7978845608f);
    float e = exp2f(u * -2.8853900818f);   // e^{-2u}
    float r = FRCP(e + 1.0f);              // sigma(2u)
    return x * r;
}
template<int CTRL>
__device__ __forceinline__ float dppadd(float s) {
    int v = __builtin_amdgcn_update_dpp(0, __float_as_int(s), CTRL, 0xF, 0xF, true);
    return s + __int_as_float(v);
}
__device__ __forceinline__ float rowsum16(float x) {
    x = dppadd<0x128>(x);   // ror:8
    x = dppadd<0x124>(x);   // ror:4
    x = dppadd<0x122>(x);   // ror:2
    x = dppadd<0x121>(x);   // ror:1
    return x;
}

// ---------------- K_prep: w2T (k-permuted by pi), w1T (col-91-shift), pooled
// pi(ch) = (ch&15)*16 + (ch>>4)  -- involution over 0..255
__global__ __launch_bounds__(256) void k_prep(
    const float* __restrict__ w1, const float* __restrict__ w2,
    unsigned short* __restrict__ w2T, unsigned short* __restrict__ w1T,
    unsigned int* __restrict__ pooled, int* __restrict__ done)
{
    int t = threadIdx.x, blk = blockIdx.x;
    if (blk < 16) {                      // w2T: [n=256][k=256 pi-permuted]
        __shared__ unsigned short tile[64][65];
        int tr = blk >> 2, tc = blk & 3;
        #pragma unroll
        for (int rr = 0; rr < 16; ++rr) {
            int kl = rr * 4 + (t >> 6), nl = t & 63;
            tile[kl][nl] = f2bf(w2[(size_t)(tr * 64 + kl) * 256 + tc * 64 + nl]);
        }
        __syncthreads();
        #pragma unroll
        for (int rr = 0; rr < 16; ++rr) {
            int nl = rr * 4 + (t >> 6), kl = t & 63;
            int ch = tr * 64 + kl;
            int kp = ((ch & 15) << 4) | (ch >> 4);   // pi
            w2T[(size_t)(tc * 64 + nl) * 256 + kp] = tile[kl][nl];
        }
    } else if (blk < 28) {               // w1T: [n=256][k=192], zero col 91 + tail
        __shared__ unsigned short tile[64][65];
        int idx = blk - 16;
        int tr = idx >> 2, tc = idx & 3;
        #pragma unroll
        for (int rr = 0; rr < 16; ++rr) {
            int kl = rr * 4 + (t >> 6), nl = t & 63;
            int kp = tr * 64 + kl;
            float v = 0.f;
            if (kp < 91)                       v = w1[(size_t)kp * 256 + tc * 64 + nl];
            else if (kp >= 92 && kp <= 187)    v = w1[(size_t)(kp - 1) * 256 + tc * 64 + nl];
            tile[kl][nl] = f2bf(v);
        }
        __syncthreads();
        #pragma unroll
        for (int rr = 0; rr < 16; ++rr) {
            int nl = rr * 4 + (t >> 6), kl = t & 63;
            w1T[(size_t)(tc * 64 + nl) * 192 + tr * 64 + kl] = tile[kl][nl];
        }
    } else {
        unsigned int idv = fenc(-1e19f);
        for (int q = t; q < 1024; q += 256) pooled[q] = idv;
        if (t == 0) *done = 0;
    }
}

// ---------------- K_main ---------------------------------------------------
__global__ __launch_bounds__(512, 4) void k_main(
    const float* __restrict__ xyz, const float* __restrict__ pf,
    const unsigned short* __restrict__ w1T, const unsigned short* __restrict__ w2T,
    const float* __restrict__ b1, const float* __restrict__ g1,
    const float* __restrict__ be1,
    const float* __restrict__ b2, const float* __restrict__ g2,
    const float* __restrict__ be2,
    unsigned int* __restrict__ pooled, int* __restrict__ done,
    const float* __restrict__ pw1, const float* __restrict__ pb1,
    const float* __restrict__ pg1, const float* __restrict__ pbe1,
    const float* __restrict__ pw2, const float* __restrict__ pb2,
    const float* __restrict__ pg2, const float* __restrict__ pbe2,
    float* __restrict__ out)
{
    // per-wave slabs: 16 rows; a1s (stride 200) unioned with h1s (stride 264)
    __shared__ __align__(16) unsigned short smem[8 * 4224];   // 67584 B
    __shared__ __align__(16) unsigned int epack[4 * 48];      // abs-emb bf16x2
    __shared__ unsigned long long bmask[4][64];
    __shared__ int   idxs[128];
    __shared__ float ctr[4][3];
    __shared__ unsigned int pool_s[256];
    __shared__ int   lastf;

    const int N = 4096;
    int tid = threadIdx.x, wv = tid >> 6, lane = tid & 63;
    int lo16 = lane & 15, quad = lane >> 4;
    int b = blockIdx.x & 3;                    // batch-major for L2 locality
    int i0 = (blockIdx.x >> 2) * 4;
    size_t base = (size_t)b * N;
    const float* xb = xyz + base * 3;

    // a1s row r (global 0..127): slab (r>>4), local row (r&15), stride 200
    #define AROW(r) (smem + (((r) >> 4) * 4224) + (((r) & 15) * 200))

    // P0: pool_s init + centers + abs sin-emb
    if (tid < 256) pool_s[tid] = fenc(-1e19f);
    if (tid < 12) { int p = tid / 3, a = tid - 3 * p; ctr[p][a] = xb[(i0 + p) * 3 + a]; }
    if (tid < 192) {
        int p = tid / 48, pr = tid - 48 * p;       // pair 0..47 (cols 2pr,2pr+1)
        float vals[2];
        #pragma unroll
        for (int q = 0; q < 2; ++q) {
            int cc = pr * 2 + q;
            int a = cc >> 5, wI = cc & 31;
            int jf = (wI < 16) ? wI : (wI - 16);
            float coord = xb[(i0 + p) * 3 + a];
            float fr = __expf(-0.61402269146507894f * (float)jf);
            float ang = coord * fr;
            vals[q] = (wI < 16) ? __sinf(ang) : __cosf(ang);
        }
        epack[p * 48 + pr] = pack2(vals[0], vals[1]);
    }
    // exact fp32 threshold: largest float <= (double)0.16*0.16  (validated R9)
    const double r2d = 0.16 * 0.16;
    float T = (float)r2d;
    if ((double)T > r2d) T = __uint_as_float(__float_as_uint(T) - 1u);
    // P0c phase A: each wave scans 8 chunks, all 4 centers per point load
    {
        f32x4 cA = *(const f32x4*)(xb + (size_t)i0 * 3);
        f32x4 cB = *(const f32x4*)(xb + (size_t)i0 * 3 + 4);
        f32x4 cC = *(const f32x4*)(xb + (size_t)i0 * 3 + 8);
        float cx0 = cA.x, cy0 = cA.y, cz0 = cA.z;
        float cx1 = cA.w, cy1 = cB.x, cz1 = cB.y;
        float cx2 = cB.z, cy2 = cB.w, cz2 = cC.x;
        float cx3 = cC.y, cy3 = cC.z, cz3 = cC.w;
        #pragma unroll 2
        for (int i = 0; i < 8; ++i) {
            int chunk = wv * 8 + i;
            int j = chunk * 64 + lane;
            const float* pp = xb + (size_t)j * 3;
            float px = pp[0], py = pp[1], pz = pp[2];
            float dx0 = __fsub_rn(px, cx0), dy0 = __fsub_rn(py, cy0), dz0 = __fsub_rn(pz, cz0);
            float sq0 = __fadd_rn(__fadd_rn(__fmul_rn(dx0, dx0), __fmul_rn(dy0, dy0)),
                                  __fmul_rn(dz0, dz0));
            unsigned long long m0 = __ballot(sq0 <= T);
            float dx1 = __fsub_rn(px, cx1), dy1 = __fsub_rn(py, cy1), dz1 = __fsub_rn(pz, cz1);
            float sq1 = __fadd_rn(__fadd_rn(__fmul_rn(dx1, dx1), __fmul_rn(dy1, dy1)),
                                  __fmul_rn(dz1, dz1));
            unsigned long long m1 = __ballot(sq1 <= T);
            float dx2 = __fsub_rn(px, cx2), dy2 = __fsub_rn(py, cy2), dz2 = __fsub_rn(pz, cz2);
            float sq2 = __fadd_rn(__fadd_rn(__fmul_rn(dx2, dx2), __fmul_rn(dy2, dy2)),
                                  __fmul_rn(dz2, dz2));
            unsigned long long m2 = __ballot(sq2 <= T);
            float dx3 = __fsub_rn(px, cx3), dy3 = __fsub_rn(py, cy3), dz3 = __fsub_rn(pz, cz3);
            float sq3 = __fadd_rn(__fadd_rn(__fmul_rn(dx3, dx3), __fmul_rn(dy3, dy3)),
                                  __fmul_rn(dz3, dz3));
            unsigned long long m3 = __ballot(sq3 <= T);
            if (lane == 0) {
                bmask[0][chunk] = m0; bmask[1][chunk] = m1;
                bmask[2][chunk] = m2; bmask[3][chunk] = m3;
            }
        }
    }
    __syncthreads();
    // P0c phase B: waves 0..3 select first 32 by ascending index (one center each)
    if (wv < 4) {
        int p = wv;
        unsigned long long m = bmask[p][lane];
        int c = __popcll(m);
        int inc = c;
        #pragma unroll
        for (int d = 1; d <= 32; d <<= 1) {
            int v = __shfl_up(inc, d);
            if (lane >= d) inc += v;
        }
        int exc = inc - c;
        int total = __shfl(inc, 63);
        unsigned long long lm = __ballot(m != 0ull);
        int fl = __ffsll(lm) - 1;                       // total>=1 (center in ball)
        unsigned long long mf = (unsigned long long)__shfl((long long)m, fl);
        int firstj = fl * 64 + __ffsll(mf) - 1;
        unsigned long long mm = m;
        int t = 0;
        while (mm != 0ull && (exc + t) < 32) {
            int bpos = __ffsll(mm) - 1;
            idxs[p * 32 + exc + t] = lane * 64 + bpos;
            mm &= mm - 1; ++t;
        }
        if (lane >= total && lane < 32) idxs[p * 32 + lane] = firstj;  // pad
    }
    __syncthreads();

    // P1a: gather pf -> cols 0..63, packed b128 LDS writes (128 rows x 4 segs)
    {
        int r = tid >> 2, seg = tid & 3;
        int j = idxs[r];
        const f32x4* src = (const f32x4*)(pf + (base + (size_t)j) * 64 + seg * 16);
        f32x4 v0 = src[0], v1 = src[1], v2 = src[2], v3 = src[3];
        u32x4 o0, o1;
        o0.x = pack2(v0.x, v0.y); o0.y = pack2(v0.z, v0.w);
        o0.z = pack2(v1.x, v1.y); o0.w = pack2(v1.z, v1.w);
        o1.x = pack2(v2.x, v2.y); o1.y = pack2(v2.z, v2.w);
        o1.z = pack2(v3.x, v3.y); o1.w = pack2(v3.z, v3.w);
        u32x4* dst = (u32x4*)(AROW(r) + seg * 16);
        dst[0] = o0; dst[1] = o1;
    }
    // P1b: rel xyz (64..66) + rel emb (67..90) + zeros (91, 188..191)
    {
        int r = tid & 127, part = tid >> 7;
        int p = r >> 5;
        int j = idxs[r];
        float rx = xb[j * 3]     - ctr[p][0];
        float ry = xb[j * 3 + 1] - ctr[p][1];
        float rz = xb[j * 3 + 2] - ctr[p][2];
        unsigned short* arow = AROW(r);
        if (part == 0) {
            *(unsigned int*)&arow[64] = pack2(rx, ry);
            arow[66] = f2bf(rz);
            arow[91] = 0;
            *(u32x2*)&arow[188] = (u32x2){0u, 0u};
        } else {
            int a = part - 1;
            float cv = (a == 0) ? rx : ((a == 1) ? ry : rz);
            const float fr4[4] = {1.f, 0.046415888336127774f,
                                  0.0021544346900318843f, 1e-4f};  // 10000^(-j/3)
            float sn[4], cs[4];
            #pragma unroll
            for (int tt = 0; tt < 4; ++tt) {
                float ang = cv * fr4[tt];
                sn[tt] = __sinf(ang); cs[tt] = __cosf(ang);
            }
            arow[67 + a * 8 + 0] = f2bf(sn[0]); arow[67 + a * 8 + 1] = f2bf(sn[1]);
            arow[67 + a * 8 + 2] = f2bf(sn[2]); arow[67 + a * 8 + 3] = f2bf(sn[3]);
            arow[67 + a * 8 + 4] = f2bf(cs[0]); arow[67 + a * 8 + 5] = f2bf(cs[1]);
            arow[67 + a * 8 + 6] = f2bf(cs[2]); arow[67 + a * 8 + 7] = f2bf(cs[3]);
        }
    }
    // P1c: abs emb cols 92..187 — pure b64 copies of pre-packed pairs
    {
        int r = tid >> 2, part = tid & 3, p = r >> 5;
        const u32x2* e = (const u32x2*)(epack + p * 48 + part * 12);
        u32x2* dst = (u32x2*)(AROW(r) + 92 + part * 24);
        #pragma unroll
        for (int q = 0; q < 6; ++q) dst[q] = e[q];
    }
    __syncthreads();
    // ----- from here to P6: NO barriers; each wave touches only its slab -----

    unsigned short* slab = smem + wv * 4224;

    // P2: stage-1 MFMA K=192; wave = 16 rows x 256 cols; C-init = b1
    f32x4 acc[16];
    #pragma unroll
    for (int nt = 0; nt < 16; ++nt) {
        float bv = b1[nt * 16 + lo16];
        acc[nt] = (f32x4){bv, bv, bv, bv};
    }
    #pragma unroll
    for (int ks = 0; ks < 6; ++ks) {
        bf16x8 afr = *(const bf16x8*)&slab[lo16 * 200 + ks * 32 + quad * 8];
        #pragma unroll
        for (int nt = 0; nt < 16; ++nt) {
            bf16x8 bfr = *(const bf16x8*)&w1T[(nt * 16 + lo16) * 192 + ks * 32 + quad * 8];
            acc[nt] = __builtin_amdgcn_mfma_f32_16x16x32_bf16(afr, bfr, acc[nt], 0, 0, 0);
        }
    }

    // P3: LN1 wave-local (nt-sum + DPP rowsum) -> gelu -> h1s (pi-packed)
    float muA[4], rsA[4];
    #pragma unroll
    for (int reg = 0; reg < 4; ++reg) {
        float s1 = 0.f, s2 = 0.f;
        #pragma unroll
        for (int nt = 0; nt < 16; ++nt) { float v = acc[nt][reg]; s1 += v; s2 = fmaf(v, v, s2); }
        s1 = rowsum16(s1); s2 = rowsum16(s2);
        float mu = s1 * (1.f / 256.f);
        float var = fmaxf(s2 * (1.f / 256.f) - mu * mu, 0.f);
        muA[reg] = mu; rsA[reg] = rsqrtf(var + LN_EPS);
    }
    // lane's 16 outputs (channels nt*16+lo16) land at permuted k = lo16*16+nt
    // -> contiguous 32B per (row,reg); same-wave DS ordering, no barrier.
    #pragma unroll
    for (int reg = 0; reg < 4; ++reg) {
        int lr = quad * 4 + reg;
        float mu = muA[reg], rs = rsA[reg];
        #pragma unroll
        for (int g4 = 0; g4 < 4; ++g4) {
            float v0 = gelu_fast(fmaf((acc[g4 * 4 + 0][reg] - mu) * rs,
                                      g1[(g4 * 4 + 0) * 16 + lo16], be1[(g4 * 4 + 0) * 16 + lo16]));
            float v1 = gelu_fast(fmaf((acc[g4 * 4 + 1][reg] - mu) * rs,
                                      g1[(g4 * 4 + 1) * 16 + lo16], be1[(g4 * 4 + 1) * 16 + lo16]));
            float v2 = gelu_fast(fmaf((acc[g4 * 4 + 2][reg] - mu) * rs,
                                      g1[(g4 * 4 + 2) * 16 + lo16], be1[(g4 * 4 + 2) * 16 + lo16]));
            float v3 = gelu_fast(fmaf((acc[g4 * 4 + 3][reg] - mu) * rs,
                                      g1[(g4 * 4 + 3) * 16 + lo16], be1[(g4 * 4 + 3) * 16 + lo16]));
            u32x2 wp; wp.x = pack2(v0, v1); wp.y = pack2(v2, v3);
            *(u32x2*)&slab[lr * 264 + lo16 * 16 + g4 * 4] = wp;
        }
    }

    // P4: stage-2 MFMA K=256 (pi-permuted k; w2T matches); C-init = b2
    #pragma unroll
    for (int nt = 0; nt < 16; ++nt) {
        float bv = b2[nt * 16 + lo16];
        acc[nt] = (f32x4){bv, bv, bv, bv};
    }
    #pragma unroll
    for (int ks = 0; ks < 8; ++ks) {
        bf16x8 afr = *(const bf16x8*)&slab[lo16 * 264 + ks * 32 + quad * 8];
        #pragma unroll
        for (int nt = 0; nt < 16; ++nt) {
            bf16x8 bfr = *(const bf16x8*)&w2T[(nt * 16 + lo16) * 256 + ks * 32 + quad * 8];
            acc[nt] = __builtin_amdgcn_mfma_f32_16x16x32_bf16(afr, bfr, acc[nt], 0, 0, 0);
        }
    }

    // P5: LN2 wave-local, normalize, channel-max over 16 rows -> LDS atomicMax
    #pragma unroll
    for (int reg = 0; reg < 4; ++reg) {
        float s1 = 0.f, s2 = 0.f;
        #pragma unroll
        for (int nt = 0; nt < 16; ++nt) { float v = acc[nt][reg]; s1 += v; s2 = fmaf(v, v, s2); }
        s1 = rowsum16(s1); s2 = rowsum16(s2);
        float mu = s1 * (1.f / 256.f);
        float var = fmaxf(s2 * (1.f / 256.f) - mu * mu, 0.f);
        muA[reg] = mu; rsA[reg] = rsqrtf(var + LN_EPS);
    }
    #pragma unroll
    for (int nt = 0; nt < 16; ++nt) {
        float g = g2[nt * 16 + lo16], be = be2[nt * 16 + lo16];
        float m = -1e30f;
        #pragma unroll
        for (int reg = 0; reg < 4; ++reg) {
            float v = fmaf((acc[nt][reg] - muA[reg]) * rsA[reg], g, be);
            m = fmaxf(m, v);
        }
        m = fmaxf(m, __shfl_xor(m, 16));
        m = fmaxf(m, __shfl_xor(m, 32));
        if (quad == 0) atomicMax(&pool_s[nt * 16 + lo16], fenc(m));
    }

    // P6: flush pool_s -> global, handshake, last-block final MLPs
    __syncthreads();
    if (tid < 256) atomicMax(pooled + b * 256 + tid, pool_s[tid]);
    __syncthreads();   // drains the atomics (vmcnt(0) before barrier)
    if (tid == 0) lastf = (atomicAdd(done, 1) == 4095);
    __syncthreads();
    if (!lastf) return;
    if (wv < 4) {
        int bb = wv;
        float* xw = (float*)smem + wv * 512;
        #pragma unroll
        for (int q = 0; q < 4; ++q)
            xw[q * 64 + lane] =
                fdec(atomicMax(&pooled[bb * 256 + q * 64 + lane], 0u));

        float a1[4];
        #pragma unroll
        for (int q = 0; q < 4; ++q) a1[q] = pb1[q * 64 + lane];
        #pragma unroll 4
        for (int k = 0; k < 256; ++k) {
            float xv = xw[k];
            const float* wr = pw1 + (size_t)k * 256 + lane;
            #pragma unroll
            for (int q = 0; q < 4; ++q) a1[q] = fmaf(xv, wr[q * 64], a1[q]);
        }
        float s1 = a1[0] + a1[1] + a1[2] + a1[3];
        float s2 = fmaf(a1[0], a1[0], fmaf(a1[1], a1[1],
                   fmaf(a1[2], a1[2], a1[3] * a1[3])));
        s1 = rowsum16(s1); s2 = rowsum16(s2);
        s1 += __shfl_xor(s1, 16); s2 += __shfl_xor(s2, 16);
        s1 += __shfl_xor(s1, 32); s2 += __shfl_xor(s2, 32);
        float mu = s1 * (1.f / 256.f);
        float rs = rsqrtf(fmaxf(s2 * (1.f / 256.f) - mu * mu, 0.f) + LN_EPS);
        #pragma unroll
        for (int q = 0; q < 4; ++q) {
            int c = q * 64 + lane;
            xw[256 + c] = gelu_fast(fmaf((a1[q] - mu) * rs, pg1[c], pbe1[c]));
        }

        float a2[4];
        #pragma unroll
        for (int q = 0; q < 4; ++q) a2[q] = pb2[q * 64 + lane];
        #pragma unroll 4
        for (int k = 0; k < 256; ++k) {
            float xv = xw[256 + k];
            const float* wr = pw2 + (size_t)k * 256 + lane;
            #pragma unroll
            for (int q = 0; q < 4; ++q) a2[q] = fmaf(xv, wr[q * 64], a2[q]);
        }
        s1 = a2[0] + a2[1] + a2[2] + a2[3];
        s2 = fmaf(a2[0], a2[0], fmaf(a2[1], a2[1],
             fmaf(a2[2], a2[2], a2[3] * a2[3])));
        s1 = rowsum16(s1); s2 = rowsum16(s2);
        s1 += __shfl_xor(s1, 16); s2 += __shfl_xor(s2, 16);
        s1 += __shfl_xor(s1, 32); s2 += __shfl_xor(s2, 32);
        mu = s1 * (1.f / 256.f);
        rs = rsqrtf(fmaxf(s2 * (1.f / 256.f) - mu * mu, 0.f) + LN_EPS);
        #pragma unroll
        for (int q = 0; q < 4; ++q) {
            int c = q * 64 + lane;
            out[bb * 256 + c] = fmaf((a2[q] - mu) * rs, pg2[c], pbe2[c]);
        }
    }
    #undef AROW
}

// ---------------- launch ---------------------------------------------------
extern "C" void kernel_launch(void* const* d_in, const int* in_sizes, int n_in,
                              void* d_out, int out_size, void* d_ws, size_t ws_size,
                              hipStream_t stream)
{
    char* ws = (char*)d_ws;
    unsigned short* w2T    = (unsigned short*)ws;                      // 128 KB
    unsigned short* w1T    = (unsigned short*)(ws + (128u << 10));     // 96 KB
    unsigned int*   pooled = (unsigned int*)(ws + (224u << 10));       // 4 KB
    int*            done   = (int*)(ws + (228u << 10));                // 4 B

    k_prep<<<29, 256, 0, stream>>>((const float*)d_in[2], (const float*)d_in[6],
                                   w2T, w1T, pooled, done);
    k_main<<<4096, 512, 0, stream>>>((const float*)d_in[0], (const float*)d_in[1],
                                     w1T, w2T,
                                     (const float*)d_in[3], (const float*)d_in[4],
                                     (const float*)d_in[5],
                                     (const float*)d_in[7], (const float*)d_in[8],
                                     (const float*)d_in[9], pooled, done,
                                     (const float*)d_in[10], (const float*)d_in[11],
                                     (const float*)d_in[12], (const float*)d_in[13],
                                     (const float*)d_in[14], (const float*)d_in[15],
                                     (const float*)d_in[16], (const float*)d_in[17],
                                     (float*)d_out);
}

// Round 3
// 634.795 us; speedup vs baseline: 1.5841x; 1.5841x over previous
//
#include <hip/hip_runtime.h>
#include <hip/hip_bf16.h>
#include <math.h>

// GlobalSceneTokenizer fused pipeline, f32 in/out.
// R17: occupancy play. R14/R15 both sat at 16 waves/CU (64 VGPR + 64 AGPR =
// 128 unified regs AND LDS both capped there) and measured identically ->
// resident-wave count is the controlling variable (R16 confirmed the kernel
// is latency-exposure-bound, not barrier-bound). This round: 1024-thread
// blocks, 64 rows (2 centers), wave tile 32x32 -> acc[2][2] = 16 acc regs,
// working set <= 64 TOTAL regs -> 8 waves/SIMD; LDS ~40KB, 2 blocks/CU by
// thread cap -> 32 waves/CU (full). Same cross-wave LN dataflow as R14/R15
// (reds[64][8]); per-wave weight loads stay 2 frags/ks from the wave's own
// 32-col group (NOT R16's all-column reload). Stage-2 k-permutation is now
// pi(nt*16+lo)=lo*2+nt within each 32-block (lane's 2 gelu outputs = 1 dword
// LDS write); w2T prep permuted to match. Weight hoist dropped: TLP at 8
// waves/SIMD hides cold-load latency, and peak register pressure matters more.
// a1s col map: [0..63]=pf | [64..66]=relxyz | [67..90]=relemb24 | [91]=0 |
//              [92..187]=absemb96 | [188..191]=0   (w1T rows remapped to match)

#define LN_EPS 1e-5f

typedef __attribute__((ext_vector_type(8))) short bf16x8;
typedef __attribute__((ext_vector_type(4))) float f32x4;
typedef __attribute__((ext_vector_type(2))) unsigned int u32x2;
typedef __attribute__((ext_vector_type(4))) unsigned int u32x4;

#if __has_builtin(__builtin_amdgcn_rcpf)
#define FRCP(x) __builtin_amdgcn_rcpf(x)
#else
#define FRCP(x) (1.0f / (x))
#endif

__device__ __forceinline__ unsigned short f2bf(float f) {
    unsigned int x = __float_as_uint(f);
    return (unsigned short)((x + 0x7FFFu + ((x >> 16) & 1u)) >> 16);  // RNE
}
__device__ __forceinline__ unsigned int pack2(float a, float b) {
    union { __hip_bfloat162 h; unsigned int u; } cvt;
    cvt.h = __float22bfloat162_rn(make_float2(a, b));
    return cvt.u;
}
__device__ __forceinline__ unsigned int fenc(float f) {
    unsigned int u = __float_as_uint(f);
    return (u & 0x80000000u) ? ~u : (u | 0x80000000u);
}
__device__ __forceinline__ float fdec(unsigned int u) {
    return __uint_as_float((u & 0x80000000u) ? (u & 0x7FFFFFFFu) : ~u);
}
__device__ __forceinline__ float gelu_fast(float x) {
    float x2 = x * x;
    float u = x * fmaf(0.0356774081f, x2, 0.7978845608f);
    float e = exp2f(u * -2.8853900818f);   // e^{-2u}
    float r = FRCP(e + 1.0f);              // sigma(2u)
    return x * r;
}
template<int CTRL>
__device__ __forceinline__ float dppadd(float s) {
    int v = __builtin_amdgcn_update_dpp(0, __float_as_int(s), CTRL, 0xF, 0xF, true);
    return s + __int_as_float(v);
}
__device__ __forceinline__ float rowsum16(float x) {
    x = dppadd<0x128>(x);   // ror:8
    x = dppadd<0x124>(x);   // ror:4
    x = dppadd<0x122>(x);   // ror:2
    x = dppadd<0x121>(x);   // ror:1
    return x;
}

// ---------------- K_prep: w2T (k-permuted by pi), w1T (col-91-shift), pooled
// pi within each 32-block of k: pi(nt*16+lo) = lo*2+nt  (nt in {0,1})
__global__ __launch_bounds__(256) void k_prep(
    const float* __restrict__ w1, const float* __restrict__ w2,
    unsigned short* __restrict__ w2T, unsigned short* __restrict__ w1T,
    unsigned int* __restrict__ pooled, int* __restrict__ done)
{
    int t = threadIdx.x, blk = blockIdx.x;
    if (blk < 16) {                      // w2T: [n=256][k=256 pi-permuted]
        __shared__ unsigned short tile[64][65];
        int tr = blk >> 2, tc = blk & 3;
        #pragma unroll
        for (int rr = 0; rr < 16; ++rr) {
            int kl = rr * 4 + (t >> 6), nl = t & 63;
            tile[kl][nl] = f2bf(w2[(size_t)(tr * 64 + kl) * 256 + tc * 64 + nl]);
        }
        __syncthreads();
        #pragma unroll
        for (int rr = 0; rr < 16; ++rr) {
            int nl = rr * 4 + (t >> 6), kp = t & 63;
            int g = kp >> 5, w = kp & 31;
            int kl = g * 32 + (w & 1) * 16 + (w >> 1);   // pi^-1
            w2T[(size_t)(tc * 64 + nl) * 256 + tr * 64 + kp] = tile[kl][nl];
        }
    } else if (blk < 28) {               // w1T: [n=256][k=192], zero col 91 + tail
        __shared__ unsigned short tile[64][65];
        int idx = blk - 16;
        int tr = idx >> 2, tc = idx & 3;
        #pragma unroll
        for (int rr = 0; rr < 16; ++rr) {
            int kl = rr * 4 + (t >> 6), nl = t & 63;
            int kp = tr * 64 + kl;
            float v = 0.f;
            if (kp < 91)                       v = w1[(size_t)kp * 256 + tc * 64 + nl];
            else if (kp >= 92 && kp <= 187)    v = w1[(size_t)(kp - 1) * 256 + tc * 64 + nl];
            tile[kl][nl] = f2bf(v);
        }
        __syncthreads();
        #pragma unroll
        for (int rr = 0; rr < 16; ++rr) {
            int nl = rr * 4 + (t >> 6), kl = t & 63;
            w1T[(size_t)(tc * 64 + nl) * 192 + tr * 64 + kl] = tile[kl][nl];
        }
    } else {
        unsigned int idv = fenc(-1e19f);
        for (int q = t; q < 1024; q += 256) pooled[q] = idv;
        if (t == 0) *done = 0;
    }
}

// ---------------- K_main ---------------------------------------------------
__global__ __launch_bounds__(1024, 8) void k_main(
    const float* __restrict__ xyz, const float* __restrict__ pf,
    const unsigned short* __restrict__ w1T, const unsigned short* __restrict__ w2T,
    const float* __restrict__ b1, const float* __restrict__ g1,
    const float* __restrict__ be1,
    const float* __restrict__ b2, const float* __restrict__ g2,
    const float* __restrict__ be2,
    unsigned int* __restrict__ pooled, int* __restrict__ done,
    const float* __restrict__ pw1, const float* __restrict__ pb1,
    const float* __restrict__ pg1, const float* __restrict__ pbe1,
    const float* __restrict__ pw2, const float* __restrict__ pb2,
    const float* __restrict__ pg2, const float* __restrict__ pbe2,
    float* __restrict__ out)
{
    // a1s (64 x 192+8, stride 200) unioned with h1s (64 x 256+8, stride 264)
    __shared__ __align__(16) unsigned short smem[64 * 264];   // 33792 B
    __shared__ __align__(16) unsigned int epack[2 * 48];      // abs-emb bf16x2
    __shared__ unsigned long long bmask[2][64];
    __shared__ int   idxs[64];
    __shared__ float ctr[2][3];
    __shared__ float reds[64][8][2];
    __shared__ float musig[64][2];
    __shared__ int   lastf;
    unsigned short* a1s = smem;   // stride 200
    unsigned short* h1s = smem;   // stride 264 (k-permuted within 32-blocks)

    const int N = 4096;
    int tid = threadIdx.x, wv = tid >> 6, lane = tid & 63;
    int lo16 = lane & 15, quad = lane >> 4;
    int wvM = wv >> 3, wvN = wv & 7;           // 2(M=32) x 8(N=32) wave grid
    int b = blockIdx.x & 3;                    // batch-major for L2 locality
    int i0 = (blockIdx.x >> 2) * 2;
    size_t base = (size_t)b * N;
    const float* xb = xyz + base * 3;

    // P0a: centers
    if (tid < 6) { int p = tid / 3, a = tid - 3 * p; ctr[p][a] = xb[(i0 + p) * 3 + a]; }
    // P0b: abs sin-emb packed pairs; 2 centers x 48 pairs; freq=10000^(-jf/15)
    if (tid < 96) {
        int p = tid / 48, pr = tid - 48 * p;       // pair 0..47 (cols 2pr,2pr+1)
        float vals[2];
        #pragma unroll
        for (int q = 0; q < 2; ++q) {
            int cc = pr * 2 + q;
            int a = cc >> 5, wI = cc & 31;
            int jf = (wI < 16) ? wI : (wI - 16);
            float coord = xb[(i0 + p) * 3 + a];
            float fr = __expf(-0.61402269146507894f * (float)jf);
            float ang = coord * fr;
            vals[q] = (wI < 16) ? __sinf(ang) : __cosf(ang);
        }
        epack[p * 48 + pr] = pack2(vals[0], vals[1]);
    }
    // exact fp32 threshold: largest float <= (double)0.16*0.16  (validated R9)
    const double r2d = 0.16 * 0.16;
    float T = (float)r2d;
    if ((double)T > r2d) T = __uint_as_float(__float_as_uint(T) - 1u);
    // P0c phase A: each wave scans 4 chunks, both centers per point load
    {
        float cx0 = xb[i0 * 3], cy0 = xb[i0 * 3 + 1], cz0 = xb[i0 * 3 + 2];
        float cx1 = xb[(i0 + 1) * 3], cy1 = xb[(i0 + 1) * 3 + 1], cz1 = xb[(i0 + 1) * 3 + 2];
        #pragma unroll 2
        for (int i = 0; i < 4; ++i) {
            int chunk = wv * 4 + i;
            int j = chunk * 64 + lane;
            const float* pp = xb + (size_t)j * 3;
            float px = pp[0], py = pp[1], pz = pp[2];
            float dx0 = __fsub_rn(px, cx0), dy0 = __fsub_rn(py, cy0), dz0 = __fsub_rn(pz, cz0);
            float sq0 = __fadd_rn(__fadd_rn(__fmul_rn(dx0, dx0), __fmul_rn(dy0, dy0)),
                                  __fmul_rn(dz0, dz0));
            unsigned long long m0 = __ballot(sq0 <= T);
            float dx1 = __fsub_rn(px, cx1), dy1 = __fsub_rn(py, cy1), dz1 = __fsub_rn(pz, cz1);
            float sq1 = __fadd_rn(__fadd_rn(__fmul_rn(dx1, dx1), __fmul_rn(dy1, dy1)),
                                  __fmul_rn(dz1, dz1));
            unsigned long long m1 = __ballot(sq1 <= T);
            if (lane == 0) { bmask[0][chunk] = m0; bmask[1][chunk] = m1; }
        }
    }
    __syncthreads();
    // P0c phase B: waves 0/1 select first 32 by ascending index
    if (wv < 2) {
        int p = wv;
        unsigned long long m = bmask[p][lane];
        int c = __popcll(m);
        int inc = c;
        #pragma unroll
        for (int d = 1; d <= 32; d <<= 1) {
            int v = __shfl_up(inc, d);
            if (lane >= d) inc += v;
        }
        int exc = inc - c;
        int total = __shfl(inc, 63);
        unsigned long long lm = __ballot(m != 0ull);
        int fl = __ffsll(lm) - 1;                       // total>=1 (center in ball)
        unsigned long long mf = (unsigned long long)__shfl((long long)m, fl);
        int firstj = fl * 64 + __ffsll(mf) - 1;
        unsigned long long mm = m;
        int t = 0;
        while (mm != 0ull && (exc + t) < 32) {
            int bpos = __ffsll(mm) - 1;
            idxs[p * 32 + exc + t] = lane * 64 + bpos;
            mm &= mm - 1; ++t;
        }
        if (lane >= total && lane < 32) idxs[p * 32 + lane] = firstj;  // pad
    }
    __syncthreads();

    // P1a: gather pf -> cols 0..63, packed b128 LDS writes (64 rows x 4 segs)
    if (tid < 256) {
        int r = tid >> 2, seg = tid & 3;
        int j = idxs[r];
        const f32x4* src = (const f32x4*)(pf + (base + (size_t)j) * 64 + seg * 16);
        f32x4 v0 = src[0], v1 = src[1], v2 = src[2], v3 = src[3];
        u32x4 o0, o1;
        o0.x = pack2(v0.x, v0.y); o0.y = pack2(v0.z, v0.w);
        o0.z = pack2(v1.x, v1.y); o0.w = pack2(v1.z, v1.w);
        o1.x = pack2(v2.x, v2.y); o1.y = pack2(v2.z, v2.w);
        o1.z = pack2(v3.x, v3.y); o1.w = pack2(v3.z, v3.w);
        u32x4* dst = (u32x4*)&a1s[r * 200 + seg * 16];
        dst[0] = o0; dst[1] = o1;
    }
    // P1b: rel xyz (64..66) + rel emb (67..90) + zeros (91, 188..191)
    else if (tid < 512) {
        int t2 = tid - 256;
        int r = t2 & 63, part = t2 >> 6;
        int p = r >> 5;
        int j = idxs[r];
        float rx = xb[j * 3]     - ctr[p][0];
        float ry = xb[j * 3 + 1] - ctr[p][1];
        float rz = xb[j * 3 + 2] - ctr[p][2];
        unsigned short* arow = &a1s[r * 200];
        if (part == 0) {
            *(unsigned int*)&arow[64] = pack2(rx, ry);
            arow[66] = f2bf(rz);
            arow[91] = 0;
            *(u32x2*)&arow[188] = (u32x2){0u, 0u};
        } else {
            int a = part - 1;
            float cv = (a == 0) ? rx : ((a == 1) ? ry : rz);
            const float fr4[4] = {1.f, 0.046415888336127774f,
                                  0.0021544346900318843f, 1e-4f};  // 10000^(-j/3)
            float sn[4], cs[4];
            #pragma unroll
            for (int tt = 0; tt < 4; ++tt) {
                float ang = cv * fr4[tt];
                sn[tt] = __sinf(ang); cs[tt] = __cosf(ang);
            }
            arow[67 + a * 8 + 0] = f2bf(sn[0]); arow[67 + a * 8 + 1] = f2bf(sn[1]);
            arow[67 + a * 8 + 2] = f2bf(sn[2]); arow[67 + a * 8 + 3] = f2bf(sn[3]);
            arow[67 + a * 8 + 4] = f2bf(cs[0]); arow[67 + a * 8 + 5] = f2bf(cs[1]);
            arow[67 + a * 8 + 6] = f2bf(cs[2]); arow[67 + a * 8 + 7] = f2bf(cs[3]);
        }
    }
    // P1c: abs emb cols 92..187 — pure b64 copies of pre-packed pairs
    else if (tid < 768) {
        int t2 = tid - 512;
        int r = t2 >> 2, part = t2 & 3, p = r >> 5;
        const u32x2* e = (const u32x2*)(epack + p * 48 + part * 12);
        u32x2* dst = (u32x2*)&a1s[r * 200 + 92 + part * 24];
        #pragma unroll
        for (int q = 0; q < 6; ++q) dst[q] = e[q];
    }
    __syncthreads();

    // P2: C-init = b1; stage-1 MFMA K=192; wave tile 32 rows x 32 cols
    const int arow0 = wvM * 32;
    f32x4 acc[2][2];
    {
        float b1f[2];
        #pragma unroll
        for (int nt = 0; nt < 2; ++nt) b1f[nt] = b1[wvN * 32 + nt * 16 + lo16];
        #pragma unroll
        for (int mt = 0; mt < 2; ++mt)
            #pragma unroll
            for (int nt = 0; nt < 2; ++nt)
                #pragma unroll
                for (int reg = 0; reg < 4; ++reg) acc[mt][nt][reg] = b1f[nt];
    }
    for (int ks = 0; ks < 6; ++ks) {
        bf16x8 bfr[2];
        #pragma unroll
        for (int nt = 0; nt < 2; ++nt) {
            int n = wvN * 32 + nt * 16 + lo16;
            bfr[nt] = *(const bf16x8*)&w1T[n * 192 + ks * 32 + quad * 8];
        }
        #pragma unroll
        for (int mt = 0; mt < 2; ++mt) {
            bf16x8 afr = *(const bf16x8*)&a1s[(arow0 + mt * 16 + lo16) * 200 + ks * 32 + quad * 8];
            #pragma unroll
            for (int nt = 0; nt < 2; ++nt)
                acc[mt][nt] = __builtin_amdgcn_mfma_f32_16x16x32_bf16(
                    afr, bfr[nt], acc[mt][nt], 0, 0, 0);
        }
    }

    // P3: LN1 stats (DPP + cross-wave reds[64][8]) -> gelu -> h1s (pi-packed)
    #pragma unroll
    for (int mt = 0; mt < 2; ++mt) {
        #pragma unroll
        for (int reg = 0; reg < 4; ++reg) {
            float s1 = 0.f, s2 = 0.f;
            #pragma unroll
            for (int nt = 0; nt < 2; ++nt) { float v = acc[mt][nt][reg]; s1 += v; s2 = fmaf(v, v, s2); }
            s1 = rowsum16(s1); s2 = rowsum16(s2);
            if (lo16 == 0) {
                int r = arow0 + mt * 16 + quad * 4 + reg;
                reds[r][wvN][0] = s1; reds[r][wvN][1] = s2;
            }
        }
    }
    __syncthreads();   // reds ready; all waves done reading a1s
    if (tid < 64) {
        int r = tid;
        float s1 = 0.f, s2 = 0.f;
        #pragma unroll
        for (int g = 0; g < 8; ++g) { s1 += reds[r][g][0]; s2 += reds[r][g][1]; }
        float mu = s1 * (1.f / 256.f);
        float var = fmaxf(s2 * (1.f / 256.f) - mu * mu, 0.f);
        musig[r][0] = mu; musig[r][1] = rsqrtf(var + LN_EPS);
    }
    __syncthreads();
    {
        float g1f[2], be1f[2];
        #pragma unroll
        for (int nt = 0; nt < 2; ++nt) {
            int n = wvN * 32 + nt * 16 + lo16;
            g1f[nt] = g1[n]; be1f[nt] = be1[n];
        }
        #pragma unroll
        for (int mt = 0; mt < 2; ++mt) {
            #pragma unroll
            for (int reg = 0; reg < 4; ++reg) {
                int r = arow0 + mt * 16 + quad * 4 + reg;
                float mu = musig[r][0], rs = musig[r][1];
                float v0 = gelu_fast(fmaf((acc[mt][0][reg] - mu) * rs, g1f[0], be1f[0]));
                float v1 = gelu_fast(fmaf((acc[mt][1][reg] - mu) * rs, g1f[1], be1f[1]));
                // lane's 2 outputs land at permuted k = lo16*2 + nt (in wvN's 32-block)
                *(unsigned int*)&h1s[r * 264 + wvN * 32 + lo16 * 2] = pack2(v0, v1);
            }
        }
    }
    __syncthreads();   // h1s ready

    // P4: stage-2 MFMA K=256 (pi-permuted k; w2T matches); C-init = b2
    {
        float b2f[2];
        #pragma unroll
        for (int nt = 0; nt < 2; ++nt) b2f[nt] = b2[wvN * 32 + nt * 16 + lo16];
        #pragma unroll
        for (int mt = 0; mt < 2; ++mt)
            #pragma unroll
            for (int nt = 0; nt < 2; ++nt)
                #pragma unroll
                for (int reg = 0; reg < 4; ++reg) acc[mt][nt][reg] = b2f[nt];
    }
    for (int ks = 0; ks < 8; ++ks) {
        bf16x8 bfr[2], afr[2];
        #pragma unroll
        for (int nt = 0; nt < 2; ++nt) {
            int n = wvN * 32 + nt * 16 + lo16;
            bfr[nt] = *(const bf16x8*)&w2T[n * 256 + ks * 32 + quad * 8];
        }
        #pragma unroll
        for (int mt = 0; mt < 2; ++mt)
            afr[mt] = *(const bf16x8*)&h1s[(arow0 + mt * 16 + lo16) * 264 + ks * 32 + quad * 8];
        #pragma unroll
        for (int mt = 0; mt < 2; ++mt)
            #pragma unroll
            for (int nt = 0; nt < 2; ++nt)
                acc[mt][nt] = __builtin_amdgcn_mfma_f32_16x16x32_bf16(
                    afr[mt], bfr[nt], acc[mt][nt], 0, 0, 0);
    }

    // P5: LN2 stats (DPP + reds), normalize, col-max -> atomicMax
    {
        #pragma unroll
        for (int mt = 0; mt < 2; ++mt) {
            #pragma unroll
            for (int reg = 0; reg < 4; ++reg) {
                float s1 = 0.f, s2 = 0.f;
                #pragma unroll
                for (int nt = 0; nt < 2; ++nt) { float v = acc[mt][nt][reg]; s1 += v; s2 = fmaf(v, v, s2); }
                s1 = rowsum16(s1); s2 = rowsum16(s2);
                if (lo16 == 0) {
                    int r = arow0 + mt * 16 + quad * 4 + reg;
                    reds[r][wvN][0] = s1; reds[r][wvN][1] = s2;
                }
            }
        }
        __syncthreads();
        if (tid < 64) {
            int r = tid;
            float s1 = 0.f, s2 = 0.f;
            #pragma unroll
            for (int g = 0; g < 8; ++g) { s1 += reds[r][g][0]; s2 += reds[r][g][1]; }
            float mu = s1 * (1.f / 256.f);
            float var = fmaxf(s2 * (1.f / 256.f) - mu * mu, 0.f);
            musig[r][0] = mu; musig[r][1] = rsqrtf(var + LN_EPS);
        }
        __syncthreads();

        float g2f[2], be2f[2];
        #pragma unroll
        for (int nt = 0; nt < 2; ++nt) {
            int n = wvN * 32 + nt * 16 + lo16;
            g2f[nt] = g2[n]; be2f[nt] = be2[n];
        }
        float mx[2] = {-1e30f, -1e30f};
        #pragma unroll
        for (int mt = 0; mt < 2; ++mt) {
            #pragma unroll
            for (int reg = 0; reg < 4; ++reg) {
                int r = arow0 + mt * 16 + quad * 4 + reg;
                float mu = musig[r][0], rs = musig[r][1];
                #pragma unroll
                for (int nt = 0; nt < 2; ++nt) {
                    float v = fmaf((acc[mt][nt][reg] - mu) * rs, g2f[nt], be2f[nt]);
                    mx[nt] = fmaxf(mx[nt], v);
                }
            }
        }
        #pragma unroll
        for (int nt = 0; nt < 2; ++nt) {
            mx[nt] = fmaxf(mx[nt], __shfl_xor(mx[nt], 16));
            mx[nt] = fmaxf(mx[nt], __shfl_xor(mx[nt], 32));
        }
        if (quad == 0) {
            #pragma unroll
            for (int nt = 0; nt < 2; ++nt)
                atomicMax(pooled + b * 256 + wvN * 32 + nt * 16 + lo16, fenc(mx[nt]));
        }
    }

    // P6: handshake (no fences) + last-block final MLPs (validated R8)
    __syncthreads();
    if (tid == 0) lastf = (atomicAdd(done, 1) == 8191);
    __syncthreads();
    if (!lastf) return;
    if (wv < 4) {
        int bb = wv;
        float* xw = (float*)smem + wv * 512;
        #pragma unroll
        for (int q = 0; q < 4; ++q)
            xw[q * 64 + lane] =
                fdec(atomicMax(&pooled[bb * 256 + q * 64 + lane], 0u));

        float a1[4];
        #pragma unroll
        for (int q = 0; q < 4; ++q) a1[q] = pb1[q * 64 + lane];
        #pragma unroll 4
        for (int k = 0; k < 256; ++k) {
            float xv = xw[k];
            const float* wr = pw1 + (size_t)k * 256 + lane;
            #pragma unroll
            for (int q = 0; q < 4; ++q) a1[q] = fmaf(xv, wr[q * 64], a1[q]);
        }
        float s1 = a1[0] + a1[1] + a1[2] + a1[3];
        float s2 = fmaf(a1[0], a1[0], fmaf(a1[1], a1[1],
                   fmaf(a1[2], a1[2], a1[3] * a1[3])));
        s1 = rowsum16(s1); s2 = rowsum16(s2);
        s1 += __shfl_xor(s1, 16); s2 += __shfl_xor(s2, 16);
        s1 += __shfl_xor(s1, 32); s2 += __shfl_xor(s2, 32);
        float mu = s1 * (1.f / 256.f);
        float rs = rsqrtf(fmaxf(s2 * (1.f / 256.f) - mu * mu, 0.f) + LN_EPS);
        #pragma unroll
        for (int q = 0; q < 4; ++q) {
            int c = q * 64 + lane;
            xw[256 + c] = gelu_fast(fmaf((a1[q] - mu) * rs, pg1[c], pbe1[c]));
        }

        float a2[4];
        #pragma unroll
        for (int q = 0; q < 4; ++q) a2[q] = pb2[q * 64 + lane];
        #pragma unroll 4
        for (int k = 0; k < 256; ++k) {
            float xv = xw[256 + k];
            const float* wr = pw2 + (size_t)k * 256 + lane;
            #pragma unroll
            for (int q = 0; q < 4; ++q) a2[q] = fmaf(xv, wr[q * 64], a2[q]);
        }
        s1 = a2[0] + a2[1] + a2[2] + a2[3];
        s2 = fmaf(a2[0], a2[0], fmaf(a2[1], a2[1],
             fmaf(a2[2], a2[2], a2[3] * a2[3])));
        s1 = rowsum16(s1); s2 = rowsum16(s2);
        s1 += __shfl_xor(s1, 16); s2 += __shfl_xor(s2, 16);
        s1 += __shfl_xor(s1, 32); s2 += __shfl_xor(s2, 32);
        mu = s1 * (1.f / 256.f);
        rs = rsqrtf(fmaxf(s2 * (1.f / 256.f) - mu * mu, 0.f) + LN_EPS);
        #pragma unroll
        for (int q = 0; q < 4; ++q) {
            int c = q * 64 + lane;
            out[bb * 256 + c] = fmaf((a2[q] - mu) * rs, pg2[c], pbe2[c]);
        }
    }
}

// ---------------- launch ---------------------------------------------------
extern "C" void kernel_launch(void* const* d_in, const int* in_sizes, int n_in,
                              void* d_out, int out_size, void* d_ws, size_t ws_size,
                              hipStream_t stream)
{
    char* ws = (char*)d_ws;
    unsigned short* w2T    = (unsigned short*)ws;                      // 128 KB
    unsigned short* w1T    = (unsigned short*)(ws + (128u << 10));     // 96 KB
    unsigned int*   pooled = (unsigned int*)(ws + (224u << 10));       // 4 KB
    int*            done   = (int*)(ws + (228u << 10));                // 4 B

    k_prep<<<29, 256, 0, stream>>>((const float*)d_in[2], (const float*)d_in[6],
                                   w2T, w1T, pooled, done);
    k_main<<<8192, 1024, 0, stream>>>((const float*)d_in[0], (const float*)d_in[1],
                                      w1T, w2T,
                                      (const float*)d_in[3], (const float*)d_in[4],
                                      (const float*)d_in[5],
                                      (const float*)d_in[7], (const float*)d_in[8],
                                      (const float*)d_in[9], pooled, done,
                                      (const float*)d_in[10], (const float*)d_in[11],
                                      (const float*)d_in[12], (const float*)d_in[13],
                                      (const float*)d_in[14], (const float*)d_in[15],
                                      (const float*)d_in[16], (const float*)d_in[17],
                                      (float*)d_out);
}

// Round 4
// 407.248 us; speedup vs baseline: 2.4691x; 1.5587x over previous
//
#include <hip/hip_runtime.h>
#include <hip/hip_bf16.h>
#include <math.h>

// GlobalSceneTokenizer fused pipeline, f32 in/out.
// R18: algebraic factoring. Stage-1 input [pf_j | rel_{j,c} | abs_c]@w1 is
// 32x redundant in the pf part (per point) and abs part (per center).
// k_pre precomputes U[j]=pf_j@w1a and V'[c]=absemb_c@w1c+b1 ONCE per point
// (f32 -> identical numerics to the fused f32 MFMA accumulation, just a
// different associativity order). k_main stage-1 collapses 6 K-steps -> 1
// (rel, K=32) with C-init = gather(U[j]) + V'[c]: deletes 80 MFMA + 40
// frag-loads per wave + all pf gather/pack (P1a) + abs trig/copies
// (P0b/P1c). U/V stored pi-permuted (lo16*4+nt within 64-blocks) so C-init
// is 16 coalesced f32x4 loads/lane. P3..P6 = proven R15 dataflow
// (128 rows, 8 waves 2Mx4N, h1s stride 264, 16 waves/CU).
// rel tile col map: [0..2]=relxyz | [3..26]=relemb24 | [27..31]=0
// (w1bT rows = w1 rows 64..90 + zero pad)

#define LN_EPS 1e-5f

typedef __attribute__((ext_vector_type(8))) short bf16x8;
typedef __attribute__((ext_vector_type(4))) float f32x4;
typedef __attribute__((ext_vector_type(2))) unsigned int u32x2;
typedef __attribute__((ext_vector_type(4))) unsigned int u32x4;

#if __has_builtin(__builtin_amdgcn_rcpf)
#define FRCP(x) __builtin_amdgcn_rcpf(x)
#else
#define FRCP(x) (1.0f / (x))
#endif

__device__ __forceinline__ unsigned short f2bf(float f) {
    unsigned int x = __float_as_uint(f);
    return (unsigned short)((x + 0x7FFFu + ((x >> 16) & 1u)) >> 16);  // RNE
}
__device__ __forceinline__ unsigned int pack2(float a, float b) {
    union { __hip_bfloat162 h; unsigned int u; } cvt;
    cvt.h = __float22bfloat162_rn(make_float2(a, b));
    return cvt.u;
}
__device__ __forceinline__ unsigned int fenc(float f) {
    unsigned int u = __float_as_uint(f);
    return (u & 0x80000000u) ? ~u : (u | 0x80000000u);
}
__device__ __forceinline__ float fdec(unsigned int u) {
    return __uint_as_float((u & 0x80000000u) ? (u & 0x7FFFFFFFu) : ~u);
}
__device__ __forceinline__ float gelu_fast(float x) {
    float x2 = x * x;
    float u = x * fmaf(0.0356774081f, x2, 0.7978845608f);
    float e = exp2f(u * -2.8853900818f);   // e^{-2u}
    float r = FRCP(e + 1.0f);              // sigma(2u)
    return x * r;
}
template<int CTRL>
__device__ __forceinline__ float dppadd(float s) {
    int v = __builtin_amdgcn_update_dpp(0, __float_as_int(s), CTRL, 0xF, 0xF, true);
    return s + __int_as_float(v);
}
__device__ __forceinline__ float rowsum16(float x) {
    x = dppadd<0x128>(x);   // ror:8
    x = dppadd<0x124>(x);   // ror:4
    x = dppadd<0x122>(x);   // ror:2
    x = dppadd<0x121>(x);   // ror:1
    return x;
}

// ---------------- K_prep ----------------------------------------------------
// blk 0..15 : w2T [n=256][k=256], k pi-permuted: pi(nt*16+lo)=lo*4+nt per 64-blk
// blk 16..19: w1aT [n=256][k=64]   (w1 rows 0..63, pf part)
// blk 20..27: w1cT [n=256][k=96]   (w1 rows 91..186, abs part)
// blk 28    : w1bT [n=256][k=32]   (w1 rows 64..90 rel part, pad 0)
// blk 29    : pooled + done init
__global__ __launch_bounds__(256) void k_prep(
    const float* __restrict__ w1, const float* __restrict__ w2,
    unsigned short* __restrict__ w2T, unsigned short* __restrict__ w1aT,
    unsigned short* __restrict__ w1cT, unsigned short* __restrict__ w1bT,
    unsigned int* __restrict__ pooled, int* __restrict__ done)
{
    int t = threadIdx.x, blk = blockIdx.x;
    if (blk < 16) {                      // w2T: [n=256][k=256 permuted]
        __shared__ unsigned short tile[64][65];
        int tr = blk >> 2, tc = blk & 3;
        #pragma unroll
        for (int rr = 0; rr < 16; ++rr) {
            int kl = rr * 4 + (t >> 6), nl = t & 63;
            tile[kl][nl] = f2bf(w2[(size_t)(tr * 64 + kl) * 256 + tc * 64 + nl]);
        }
        __syncthreads();
        #pragma unroll
        for (int rr = 0; rr < 16; ++rr) {
            int nl = rr * 4 + (t >> 6), kp = t & 63;
            int kl = (kp & 3) * 16 + (kp >> 2);      // pi^-1
            w2T[(size_t)(tc * 64 + nl) * 256 + tr * 64 + kp] = tile[kl][nl];
        }
    } else if (blk < 20) {               // w1aT: [256][64]
        __shared__ unsigned short tile[64][65];
        int tc = blk - 16;
        #pragma unroll
        for (int rr = 0; rr < 16; ++rr) {
            int kl = rr * 4 + (t >> 6), nl = t & 63;
            tile[kl][nl] = f2bf(w1[(size_t)kl * 256 + tc * 64 + nl]);
        }
        __syncthreads();
        #pragma unroll
        for (int rr = 0; rr < 16; ++rr) {
            int nl = rr * 4 + (t >> 6), kl = t & 63;
            w1aT[(size_t)(tc * 64 + nl) * 64 + kl] = tile[kl][nl];
        }
    } else if (blk < 28) {               // w1cT: [256][96] from w1 rows 91..186
        __shared__ unsigned short tile[64][65];
        int idx = blk - 20;
        int tr2 = idx >> 2, tc = idx & 3;
        #pragma unroll
        for (int rr = 0; rr < 16; ++rr) {
            int kl = rr * 4 + (t >> 6), nl = t & 63;
            int k = tr2 * 64 + kl;
            float v = 0.f;
            if (k < 96) v = w1[(size_t)(91 + k) * 256 + tc * 64 + nl];
            tile[kl][nl] = f2bf(v);
        }
        __syncthreads();
        #pragma unroll
        for (int rr = 0; rr < 16; ++rr) {
            int nl = rr * 4 + (t >> 6), kl = t & 63;
            int k = tr2 * 64 + kl;
            if (k < 96)
                w1cT[(size_t)(tc * 64 + nl) * 96 + k] = tile[kl][nl];
        }
    } else if (blk == 28) {              // w1bT: [256][32], rel part
        int n = t;
        #pragma unroll
        for (int k = 0; k < 32; ++k) {
            unsigned short v = 0;
            if (k < 27) v = f2bf(w1[(size_t)(64 + k) * 256 + n]);
            w1bT[(size_t)n * 32 + k] = v;
        }
    } else {
        unsigned int idv = fenc(-1e19f);
        for (int q = t; q < 1024; q += 256) pooled[q] = idv;
        if (t == 0) *done = 0;
    }
}

// ---------------- K_pre: U[p]=pf@w1a, V'[p]=absemb@w1c+b1 (pi-permuted f32) --
// 256 blocks x 256 threads; 64 rows/block; wave = 64 rows x 64 cols (wvN=wv)
__global__ __launch_bounds__(256) void k_pre(
    const float* __restrict__ xyz, const float* __restrict__ pf,
    const unsigned short* __restrict__ w1aT, const unsigned short* __restrict__ w1cT,
    const float* __restrict__ b1,
    float* __restrict__ U_p, float* __restrict__ V_p)
{
    __shared__ __align__(16) unsigned short ptile[64 * 72];    // pf bf16
    __shared__ __align__(16) unsigned short etile[64 * 104];   // abs emb bf16
    int tid = threadIdx.x, wv = tid >> 6, lane = tid & 63;
    int lo16 = lane & 15, quad = lane >> 4;
    int rows0 = blockIdx.x * 64;

    // stage pf (64 rows x 64 cols)
    {
        int r = tid >> 2, seg = tid & 3;
        const f32x4* src = (const f32x4*)(pf + (size_t)(rows0 + r) * 64 + seg * 16);
        f32x4 v0 = src[0], v1 = src[1], v2 = src[2], v3 = src[3];
        u32x4 o0, o1;
        o0.x = pack2(v0.x, v0.y); o0.y = pack2(v0.z, v0.w);
        o0.z = pack2(v1.x, v1.y); o0.w = pack2(v1.z, v1.w);
        o1.x = pack2(v2.x, v2.y); o1.y = pack2(v2.z, v2.w);
        o1.z = pack2(v3.x, v3.y); o1.w = pack2(v3.z, v3.w);
        u32x4* dst = (u32x4*)&ptile[r * 72 + seg * 16];
        dst[0] = o0; dst[1] = o1;
    }
    // stage abs sin-emb (64 rows x 96 cols = 48 pairs); freq=10000^(-jf/15)
    {
        int r = tid & 63, grp = tid >> 6;
        float c0 = xyz[(size_t)(rows0 + r) * 3];
        float c1 = xyz[(size_t)(rows0 + r) * 3 + 1];
        float c2 = xyz[(size_t)(rows0 + r) * 3 + 2];
        #pragma unroll
        for (int q = 0; q < 12; ++q) {
            int pr = grp * 12 + q;
            float vals[2];
            #pragma unroll
            for (int qq = 0; qq < 2; ++qq) {
                int cc = pr * 2 + qq;
                int a = cc >> 5, wI = cc & 31;
                int jf = (wI < 16) ? wI : (wI - 16);
                float coord = (a == 0) ? c0 : ((a == 1) ? c1 : c2);
                float fr = __expf(-0.61402269146507894f * (float)jf);
                float ang = coord * fr;
                vals[qq] = (wI < 16) ? __sinf(ang) : __cosf(ang);
            }
            *(unsigned int*)&etile[r * 104 + 2 * pr] = pack2(vals[0], vals[1]);
        }
    }
    __syncthreads();

    // U GEMM: K=64, C-init 0
    f32x4 acc[4][4];
    #pragma unroll
    for (int mt = 0; mt < 4; ++mt)
        #pragma unroll
        for (int nt = 0; nt < 4; ++nt) acc[mt][nt] = (f32x4){0.f, 0.f, 0.f, 0.f};
    #pragma unroll
    for (int ks = 0; ks < 2; ++ks) {
        bf16x8 bfr[4];
        #pragma unroll
        for (int nt = 0; nt < 4; ++nt) {
            int n = wv * 64 + nt * 16 + lo16;
            bfr[nt] = *(const bf16x8*)&w1aT[(size_t)n * 64 + ks * 32 + quad * 8];
        }
        #pragma unroll
        for (int mt = 0; mt < 4; ++mt) {
            bf16x8 afr = *(const bf16x8*)&ptile[(mt * 16 + lo16) * 72 + ks * 32 + quad * 8];
            #pragma unroll
            for (int nt = 0; nt < 4; ++nt)
                acc[mt][nt] = __builtin_amdgcn_mfma_f32_16x16x32_bf16(
                    afr, bfr[nt], acc[mt][nt], 0, 0, 0);
        }
    }
    #pragma unroll
    for (int mt = 0; mt < 4; ++mt)
        #pragma unroll
        for (int reg = 0; reg < 4; ++reg) {
            f32x4 o = {acc[mt][0][reg], acc[mt][1][reg], acc[mt][2][reg], acc[mt][3][reg]};
            *(f32x4*)&U_p[(size_t)(rows0 + mt * 16 + quad * 4 + reg) * 256 + wv * 64 + lo16 * 4] = o;
        }

    // V GEMM: K=96, C-init = b1 (folded)
    {
        float b1f[4];
        #pragma unroll
        for (int nt = 0; nt < 4; ++nt) b1f[nt] = b1[wv * 64 + nt * 16 + lo16];
        #pragma unroll
        for (int mt = 0; mt < 4; ++mt)
            #pragma unroll
            for (int nt = 0; nt < 4; ++nt)
                #pragma unroll
                for (int reg = 0; reg < 4; ++reg) acc[mt][nt][reg] = b1f[nt];
    }
    #pragma unroll
    for (int ks = 0; ks < 3; ++ks) {
        bf16x8 bfr[4];
        #pragma unroll
        for (int nt = 0; nt < 4; ++nt) {
            int n = wv * 64 + nt * 16 + lo16;
            bfr[nt] = *(const bf16x8*)&w1cT[(size_t)n * 96 + ks * 32 + quad * 8];
        }
        #pragma unroll
        for (int mt = 0; mt < 4; ++mt) {
            bf16x8 afr = *(const bf16x8*)&etile[(mt * 16 + lo16) * 104 + ks * 32 + quad * 8];
            #pragma unroll
            for (int nt = 0; nt < 4; ++nt)
                acc[mt][nt] = __builtin_amdgcn_mfma_f32_16x16x32_bf16(
                    afr, bfr[nt], acc[mt][nt], 0, 0, 0);
        }
    }
    #pragma unroll
    for (int mt = 0; mt < 4; ++mt)
        #pragma unroll
        for (int reg = 0; reg < 4; ++reg) {
            f32x4 o = {acc[mt][0][reg], acc[mt][1][reg], acc[mt][2][reg], acc[mt][3][reg]};
            *(f32x4*)&V_p[(size_t)(rows0 + mt * 16 + quad * 4 + reg) * 256 + wv * 64 + lo16 * 4] = o;
        }
}

// ---------------- K_main ---------------------------------------------------
__global__ __launch_bounds__(512, 4) void k_main(
    const float* __restrict__ xyz,
    const unsigned short* __restrict__ w1bT, const unsigned short* __restrict__ w2T,
    const float* __restrict__ U_p, const float* __restrict__ V_p,
    const float* __restrict__ g1, const float* __restrict__ be1,
    const float* __restrict__ b2, const float* __restrict__ g2,
    const float* __restrict__ be2,
    unsigned int* __restrict__ pooled, int* __restrict__ done,
    const float* __restrict__ pw1, const float* __restrict__ pb1,
    const float* __restrict__ pg1, const float* __restrict__ pbe1,
    const float* __restrict__ pw2, const float* __restrict__ pb2,
    const float* __restrict__ pg2, const float* __restrict__ pbe2,
    float* __restrict__ out)
{
    // rels (128 x 32+8, stride 40) unioned with h1s (128 x 256+8, stride 264)
    __shared__ __align__(16) unsigned short smem[128 * 264];   // 67584 B
    __shared__ unsigned long long bmask[4][64];
    __shared__ int   idxs[128];
    __shared__ float ctr[4][3];
    __shared__ float reds[128][4][2];
    __shared__ float musig[128][2];
    __shared__ int   lastf;
    unsigned short* rels = smem;  // stride 40 (dead once stage-1 MFMAs done)
    unsigned short* h1s  = smem;  // stride 264 (k-permuted within 64-blocks)

    const int N = 4096;
    int tid = threadIdx.x, wv = tid >> 6, lane = tid & 63;
    int lo16 = lane & 15, quad = lane >> 4;
    int wvM = wv >> 2, wvN = wv & 3;           // 2(M) x 4(N) wave grid
    int b = blockIdx.x & 3;                    // batch-major for L2 locality
    int i0 = (blockIdx.x >> 2) * 4;
    size_t base = (size_t)b * N;
    const float* xb = xyz + base * 3;

    // hoisted: rel-part stage-1 weights (independent of LDS)
    bf16x8 bfrR[4];
    #pragma unroll
    for (int nt = 0; nt < 4; ++nt) {
        int n = wvN * 64 + nt * 16 + lo16;
        bfrR[nt] = *(const bf16x8*)&w1bT[(size_t)n * 32 + quad * 8];
    }

    // P0a: centers
    if (tid < 12) { int p = tid / 3, a = tid - 3 * p; ctr[p][a] = xb[(i0 + p) * 3 + a]; }
    // exact fp32 threshold: largest float <= (double)0.16*0.16  (validated R9)
    const double r2d = 0.16 * 0.16;
    float T = (float)r2d;
    if ((double)T > r2d) T = __uint_as_float(__float_as_uint(T) - 1u);
    // P0c phase A: each wave scans 8 chunks, all 4 centers per point load
    {
        f32x4 cA = *(const f32x4*)(xb + (size_t)i0 * 3);
        f32x4 cB = *(const f32x4*)(xb + (size_t)i0 * 3 + 4);
        f32x4 cC = *(const f32x4*)(xb + (size_t)i0 * 3 + 8);
        float cx0 = cA.x, cy0 = cA.y, cz0 = cA.z;
        float cx1 = cA.w, cy1 = cB.x, cz1 = cB.y;
        float cx2 = cB.z, cy2 = cB.w, cz2 = cC.x;
        float cx3 = cC.y, cy3 = cC.z, cz3 = cC.w;
        #pragma unroll 2
        for (int i = 0; i < 8; ++i) {
            int chunk = wv * 8 + i;
            int j = chunk * 64 + lane;
            const float* pp = xb + (size_t)j * 3;
            float px = pp[0], py = pp[1], pz = pp[2];
            float dx0 = __fsub_rn(px, cx0), dy0 = __fsub_rn(py, cy0), dz0 = __fsub_rn(pz, cz0);
            float sq0 = __fadd_rn(__fadd_rn(__fmul_rn(dx0, dx0), __fmul_rn(dy0, dy0)),
                                  __fmul_rn(dz0, dz0));
            unsigned long long m0 = __ballot(sq0 <= T);
            float dx1 = __fsub_rn(px, cx1), dy1 = __fsub_rn(py, cy1), dz1 = __fsub_rn(pz, cz1);
            float sq1 = __fadd_rn(__fadd_rn(__fmul_rn(dx1, dx1), __fmul_rn(dy1, dy1)),
                                  __fmul_rn(dz1, dz1));
            unsigned long long m1 = __ballot(sq1 <= T);
            float dx2 = __fsub_rn(px, cx2), dy2 = __fsub_rn(py, cy2), dz2 = __fsub_rn(pz, cz2);
            float sq2 = __fadd_rn(__fadd_rn(__fmul_rn(dx2, dx2), __fmul_rn(dy2, dy2)),
                                  __fmul_rn(dz2, dz2));
            unsigned long long m2 = __ballot(sq2 <= T);
            float dx3 = __fsub_rn(px, cx3), dy3 = __fsub_rn(py, cy3), dz3 = __fsub_rn(pz, cz3);
            float sq3 = __fadd_rn(__fadd_rn(__fmul_rn(dx3, dx3), __fmul_rn(dy3, dy3)),
                                  __fmul_rn(dz3, dz3));
            unsigned long long m3 = __ballot(sq3 <= T);
            if (lane == 0) {
                bmask[0][chunk] = m0; bmask[1][chunk] = m1;
                bmask[2][chunk] = m2; bmask[3][chunk] = m3;
            }
        }
    }
    __syncthreads();
    // P0c phase B: waves 0..3 select first 32 by ascending index (one center each)
    if (wv < 4) {
        int p = wv;
        unsigned long long m = bmask[p][lane];
        int c = __popcll(m);
        int inc = c;
        #pragma unroll
        for (int d = 1; d <= 32; d <<= 1) {
            int v = __shfl_up(inc, d);
            if (lane >= d) inc += v;
        }
        int exc = inc - c;
        int total = __shfl(inc, 63);
        unsigned long long lm = __ballot(m != 0ull);
        int fl = __ffsll(lm) - 1;                       // total>=1 (center in ball)
        unsigned long long mf = (unsigned long long)__shfl((long long)m, fl);
        int firstj = fl * 64 + __ffsll(mf) - 1;
        unsigned long long mm = m;
        int t = 0;
        while (mm != 0ull && (exc + t) < 32) {
            int bpos = __ffsll(mm) - 1;
            idxs[p * 32 + exc + t] = lane * 64 + bpos;
            mm &= mm - 1; ++t;
        }
        if (lane >= total && lane < 32) idxs[p * 32 + lane] = firstj;  // pad
    }
    __syncthreads();

    // P1b: rel xyz (cols 0..2) + rel emb (3..26) + zeros (27..31)
    {
        int r = tid & 127, part = tid >> 7;
        int p = r >> 5;
        int j = idxs[r];
        float rx = xb[j * 3]     - ctr[p][0];
        float ry = xb[j * 3 + 1] - ctr[p][1];
        float rz = xb[j * 3 + 2] - ctr[p][2];
        unsigned short* arow = &rels[r * 40];
        if (part == 0) {
            *(unsigned int*)&arow[0] = pack2(rx, ry);
            arow[2] = f2bf(rz);
            arow[27] = 0;
            *(u32x2*)&arow[28] = (u32x2){0u, 0u};
        } else {
            int a = part - 1;
            float cv = (a == 0) ? rx : ((a == 1) ? ry : rz);
            const float fr4[4] = {1.f, 0.046415888336127774f,
                                  0.0021544346900318843f, 1e-4f};  // 10000^(-j/3)
            float sn[4], cs[4];
            #pragma unroll
            for (int tt = 0; tt < 4; ++tt) {
                float ang = cv * fr4[tt];
                sn[tt] = __sinf(ang); cs[tt] = __cosf(ang);
            }
            arow[3 + a * 8 + 0] = f2bf(sn[0]); arow[3 + a * 8 + 1] = f2bf(sn[1]);
            arow[3 + a * 8 + 2] = f2bf(sn[2]); arow[3 + a * 8 + 3] = f2bf(sn[3]);
            arow[3 + a * 8 + 4] = f2bf(cs[0]); arow[3 + a * 8 + 5] = f2bf(cs[1]);
            arow[3 + a * 8 + 6] = f2bf(cs[2]); arow[3 + a * 8 + 7] = f2bf(cs[3]);
        }
    }
    __syncthreads();

    // P2: C-init = U[j] + V'[c]  (b1 folded into V'); then rel MFMA K=32
    const int arow0 = wvM * 64;
    f32x4 acc[4][4];
    #pragma unroll
    for (int mt = 0; mt < 4; ++mt) {
        int cl = wvM * 2 + (mt >> 1);   // center of rows [arow0+mt*16, +16)
        f32x4 vv = *(const f32x4*)&V_p[(size_t)(base + i0 + cl) * 256 + wvN * 64 + lo16 * 4];
        #pragma unroll
        for (int reg = 0; reg < 4; ++reg) {
            int r = arow0 + mt * 16 + quad * 4 + reg;
            int j = idxs[r];
            f32x4 uu = *(const f32x4*)&U_p[(size_t)(base + j) * 256 + wvN * 64 + lo16 * 4];
            #pragma unroll
            for (int nt = 0; nt < 4; ++nt) acc[mt][nt][reg] = uu[nt] + vv[nt];
        }
    }
    #pragma unroll
    for (int mt = 0; mt < 4; ++mt) {
        bf16x8 afr = *(const bf16x8*)&rels[(arow0 + mt * 16 + lo16) * 40 + quad * 8];
        #pragma unroll
        for (int nt = 0; nt < 4; ++nt)
            acc[mt][nt] = __builtin_amdgcn_mfma_f32_16x16x32_bf16(
                afr, bfrR[nt], acc[mt][nt], 0, 0, 0);
    }

    // P3: LN1 stats (DPP + cross-wave reds) -> gelu -> h1s (pi-packed b64)
    #pragma unroll
    for (int mt = 0; mt < 4; ++mt) {
        #pragma unroll
        for (int reg = 0; reg < 4; ++reg) {
            float s1 = 0.f, s2 = 0.f;
            #pragma unroll
            for (int nt = 0; nt < 4; ++nt) { float v = acc[mt][nt][reg]; s1 += v; s2 = fmaf(v, v, s2); }
            s1 = rowsum16(s1); s2 = rowsum16(s2);
            if (lo16 == 0) {
                int r = arow0 + mt * 16 + quad * 4 + reg;
                reds[r][wvN][0] = s1; reds[r][wvN][1] = s2;
            }
        }
    }
    __syncthreads();   // reds ready; all waves done reading rels
    if (tid < 128) {
        int r = tid;
        float s1 = reds[r][0][0] + reds[r][1][0] + reds[r][2][0] + reds[r][3][0];
        float s2 = reds[r][0][1] + reds[r][1][1] + reds[r][2][1] + reds[r][3][1];
        float mu = s1 * (1.f / 256.f);
        float var = fmaxf(s2 * (1.f / 256.f) - mu * mu, 0.f);
        musig[r][0] = mu; musig[r][1] = rsqrtf(var + LN_EPS);
    }
    __syncthreads();
    {
        float g1f[4], be1f[4];
        #pragma unroll
        for (int nt = 0; nt < 4; ++nt) {
            int n = wvN * 64 + nt * 16 + lo16;
            g1f[nt] = g1[n]; be1f[nt] = be1[n];
        }
        #pragma unroll
        for (int mt = 0; mt < 4; ++mt) {
            #pragma unroll
            for (int reg = 0; reg < 4; ++reg) {
                int r = arow0 + mt * 16 + quad * 4 + reg;
                float mu = musig[r][0], rs = musig[r][1];
                float v0 = gelu_fast(fmaf((acc[mt][0][reg] - mu) * rs, g1f[0], be1f[0]));
                float v1 = gelu_fast(fmaf((acc[mt][1][reg] - mu) * rs, g1f[1], be1f[1]));
                float v2 = gelu_fast(fmaf((acc[mt][2][reg] - mu) * rs, g1f[2], be1f[2]));
                float v3 = gelu_fast(fmaf((acc[mt][3][reg] - mu) * rs, g1f[3], be1f[3]));
                u32x2 w; w.x = pack2(v0, v1); w.y = pack2(v2, v3);
                *(u32x2*)&h1s[r * 264 + wvN * 64 + lo16 * 4] = w;   // pi(n)=lo16*4+nt
            }
        }
    }
    __syncthreads();   // h1s ready

    // P4: stage-2 MFMA K=256 (pi-permuted; w2T matches); C-init = b2
    {
        float b2f[4];
        #pragma unroll
        for (int nt = 0; nt < 4; ++nt) b2f[nt] = b2[wvN * 64 + nt * 16 + lo16];
        #pragma unroll
        for (int mt = 0; mt < 4; ++mt)
            #pragma unroll
            for (int nt = 0; nt < 4; ++nt)
                #pragma unroll
                for (int reg = 0; reg < 4; ++reg) acc[mt][nt][reg] = b2f[nt];
    }
    for (int ks = 0; ks < 8; ++ks) {
        bf16x8 bfr[4], afr[4];
        #pragma unroll
        for (int nt = 0; nt < 4; ++nt) {
            int n = wvN * 64 + nt * 16 + lo16;
            bfr[nt] = *(const bf16x8*)&w2T[(size_t)n * 256 + ks * 32 + quad * 8];
        }
        #pragma unroll
        for (int mt = 0; mt < 4; ++mt)
            afr[mt] = *(const bf16x8*)&h1s[(arow0 + mt * 16 + lo16) * 264 + ks * 32 + quad * 8];
        #pragma unroll
        for (int mt = 0; mt < 4; ++mt)
            #pragma unroll
            for (int nt = 0; nt < 4; ++nt)
                acc[mt][nt] = __builtin_amdgcn_mfma_f32_16x16x32_bf16(
                    afr[mt], bfr[nt], acc[mt][nt], 0, 0, 0);
    }

    // P5: LN2 stats (DPP + reds), normalize, col-max -> atomicMax
    {
        #pragma unroll
        for (int mt = 0; mt < 4; ++mt) {
            #pragma unroll
            for (int reg = 0; reg < 4; ++reg) {
                float s1 = 0.f, s2 = 0.f;
                #pragma unroll
                for (int nt = 0; nt < 4; ++nt) { float v = acc[mt][nt][reg]; s1 += v; s2 = fmaf(v, v, s2); }
                s1 = rowsum16(s1); s2 = rowsum16(s2);
                if (lo16 == 0) {
                    int r = arow0 + mt * 16 + quad * 4 + reg;
                    reds[r][wvN][0] = s1; reds[r][wvN][1] = s2;
                }
            }
        }
        __syncthreads();
        if (tid < 128) {
            int r = tid;
            float s1 = reds[r][0][0] + reds[r][1][0] + reds[r][2][0] + reds[r][3][0];
            float s2 = reds[r][0][1] + reds[r][1][1] + reds[r][2][1] + reds[r][3][1];
            float mu = s1 * (1.f / 256.f);
            float var = fmaxf(s2 * (1.f / 256.f) - mu * mu, 0.f);
            musig[r][0] = mu; musig[r][1] = rsqrtf(var + LN_EPS);
        }
        __syncthreads();

        float g2f[4], be2f[4];
        #pragma unroll
        for (int nt = 0; nt < 4; ++nt) {
            int n = wvN * 64 + nt * 16 + lo16;
            g2f[nt] = g2[n]; be2f[nt] = be2[n];
        }
        float mx[4] = {-1e30f, -1e30f, -1e30f, -1e30f};
        #pragma unroll
        for (int mt = 0; mt < 4; ++mt) {
            #pragma unroll
            for (int reg = 0; reg < 4; ++reg) {
                int r = arow0 + mt * 16 + quad * 4 + reg;
                float mu = musig[r][0], rs = musig[r][1];
                #pragma unroll
                for (int nt = 0; nt < 4; ++nt) {
                    float v = fmaf((acc[mt][nt][reg] - mu) * rs, g2f[nt], be2f[nt]);
                    mx[nt] = fmaxf(mx[nt], v);
                }
            }
        }
        #pragma unroll
        for (int nt = 0; nt < 4; ++nt) {
            mx[nt] = fmaxf(mx[nt], __shfl_xor(mx[nt], 16));
            mx[nt] = fmaxf(mx[nt], __shfl_xor(mx[nt], 32));
        }
        if (quad == 0) {
            #pragma unroll
            for (int nt = 0; nt < 4; ++nt)
                atomicMax(pooled + b * 256 + wvN * 64 + nt * 16 + lo16, fenc(mx[nt]));
        }
    }

    // P6: handshake (no fences) + last-block final MLPs (validated R8)
    __syncthreads();
    if (tid == 0) lastf = (atomicAdd(done, 1) == 4095);
    __syncthreads();
    if (!lastf) return;
    if (wv < 4) {
        int bb = wv;
        float* xw = (float*)smem + wv * 512;
        #pragma unroll
        for (int q = 0; q < 4; ++q)
            xw[q * 64 + lane] =
                fdec(atomicMax(&pooled[bb * 256 + q * 64 + lane], 0u));

        float a1[4];
        #pragma unroll
        for (int q = 0; q < 4; ++q) a1[q] = pb1[q * 64 + lane];
        #pragma unroll 4
        for (int k = 0; k < 256; ++k) {
            float xv = xw[k];
            const float* wr = pw1 + (size_t)k * 256 + lane;
            #pragma unroll
            for (int q = 0; q < 4; ++q) a1[q] = fmaf(xv, wr[q * 64], a1[q]);
        }
        float s1 = a1[0] + a1[1] + a1[2] + a1[3];
        float s2 = fmaf(a1[0], a1[0], fmaf(a1[1], a1[1],
                   fmaf(a1[2], a1[2], a1[3] * a1[3])));
        s1 = rowsum16(s1); s2 = rowsum16(s2);
        s1 += __shfl_xor(s1, 16); s2 += __shfl_xor(s2, 16);
        s1 += __shfl_xor(s1, 32); s2 += __shfl_xor(s2, 32);
        float mu = s1 * (1.f / 256.f);
        float rs = rsqrtf(fmaxf(s2 * (1.f / 256.f) - mu * mu, 0.f) + LN_EPS);
        #pragma unroll
        for (int q = 0; q < 4; ++q) {
            int c = q * 64 + lane;
            xw[256 + c] = gelu_fast(fmaf((a1[q] - mu) * rs, pg1[c], pbe1[c]));
        }

        float a2[4];
        #pragma unroll
        for (int q = 0; q < 4; ++q) a2[q] = pb2[q * 64 + lane];
        #pragma unroll 4
        for (int k = 0; k < 256; ++k) {
            float xv = xw[256 + k];
            const float* wr = pw2 + (size_t)k * 256 + lane;
            #pragma unroll
            for (int q = 0; q < 4; ++q) a2[q] = fmaf(xv, wr[q * 64], a2[q]);
        }
        s1 = a2[0] + a2[1] + a2[2] + a2[3];
        s2 = fmaf(a2[0], a2[0], fmaf(a2[1], a2[1],
             fmaf(a2[2], a2[2], a2[3] * a2[3])));
        s1 = rowsum16(s1); s2 = rowsum16(s2);
        s1 += __shfl_xor(s1, 16); s2 += __shfl_xor(s2, 16);
        s1 += __shfl_xor(s1, 32); s2 += __shfl_xor(s2, 32);
        mu = s1 * (1.f / 256.f);
        rs = rsqrtf(fmaxf(s2 * (1.f / 256.f) - mu * mu, 0.f) + LN_EPS);
        #pragma unroll
        for (int q = 0; q < 4; ++q) {
            int c = q * 64 + lane;
            out[bb * 256 + c] = fmaf((a2[q] - mu) * rs, pg2[c], pbe2[c]);
        }
    }
}

// ---------------- launch ---------------------------------------------------
extern "C" void kernel_launch(void* const* d_in, const int* in_sizes, int n_in,
                              void* d_out, int out_size, void* d_ws, size_t ws_size,
                              hipStream_t stream)
{
    char* ws = (char*)d_ws;
    unsigned short* w2T    = (unsigned short*)ws;                      // 128 KB
    unsigned short* w1aT   = (unsigned short*)(ws + (128u << 10));     // 32 KB
    unsigned short* w1cT   = (unsigned short*)(ws + (160u << 10));     // 48 KB
    unsigned short* w1bT   = (unsigned short*)(ws + (208u << 10));     // 16 KB
    unsigned int*   pooled = (unsigned int*)(ws + (224u << 10));       // 4 KB
    int*            done   = (int*)(ws + (228u << 10));                // 4 B
    float*          U_p    = (float*)(ws + (256u << 10));              // 16 MB
    float*          V_p    = (float*)(ws + (256u << 10) + (16u << 20)); // 16 MB

    const float* xyz = (const float*)d_in[0];
    const float* pf  = (const float*)d_in[1];
    const float* w1  = (const float*)d_in[2];
    const float* b1  = (const float*)d_in[3];

    k_prep<<<30, 256, 0, stream>>>(w1, (const float*)d_in[6],
                                   w2T, w1aT, w1cT, w1bT, pooled, done);
    k_pre<<<256, 256, 0, stream>>>(xyz, pf, w1aT, w1cT, b1, U_p, V_p);
    k_main<<<4096, 512, 0, stream>>>(xyz, w1bT, w2T, U_p, V_p,
                                     (const float*)d_in[4], (const float*)d_in[5],
                                     (const float*)d_in[7], (const float*)d_in[8],
                                     (const float*)d_in[9], pooled, done,
                                     (const float*)d_in[10], (const float*)d_in[11],
                                     (const float*)d_in[12], (const float*)d_in[13],
                                     (const float*)d_in[14], (const float*)d_in[15],
                                     (const float*)d_in[16], (const float*)d_in[17],
                                     (float*)d_out);
}

// Round 5
// 402.014 us; speedup vs baseline: 2.5013x; 1.0130x over previous
//
#include <hip/hip_runtime.h>
#include <hip/hip_bf16.h>
#include <math.h>

// GlobalSceneTokenizer fused pipeline, f32 in/out.
// R19 = R18 dataflow + atomic/handshake floor removal.
// R18 (kept): stage-1 factored as U[j]=pf_j@w1a, V'[c]=absemb_c@w1c+b1
// precomputed in k_pre; k_main stage-1 = C-init gather(U)+V' + one K=32 rel
// MFMA step; stage-2 K=256 pi-permuted; proven R15 dataflow (128 rows,
// 8 waves 2Mx4N, h1s stride 264).
// R19 (new): (1) final MLPs moved to k_final (separate launch) -> deletes the
// 4096-block contended done-counter + tail barriers + block-exit drain;
// (2) per-block LDS pre-reduce pool_s[256] -> 256 coalesced global atomics
// per block (was 512 scattered); (3) pooled replicated x8 (replica =
// (blockIdx>>2)&7) -> 8x less cross-XCD line contention; k_final max-reduces
// replicas (fenc is order-preserving -> exact).
// Evidence: WRITE_SIZE=73.8MB on k_main (logical writes ~KB) = atomic line
// bouncing; 355-410us invariance across R14/R15/R18 structures = a
// structure-invariant floor.

#define LN_EPS 1e-5f

typedef __attribute__((ext_vector_type(8))) short bf16x8;
typedef __attribute__((ext_vector_type(4))) float f32x4;
typedef __attribute__((ext_vector_type(2))) unsigned int u32x2;
typedef __attribute__((ext_vector_type(4))) unsigned int u32x4;

#if __has_builtin(__builtin_amdgcn_rcpf)
#define FRCP(x) __builtin_amdgcn_rcpf(x)
#else
#define FRCP(x) (1.0f / (x))
#endif

__device__ __forceinline__ unsigned short f2bf(float f) {
    unsigned int x = __float_as_uint(f);
    return (unsigned short)((x + 0x7FFFu + ((x >> 16) & 1u)) >> 16);  // RNE
}
__device__ __forceinline__ unsigned int pack2(float a, float b) {
    union { __hip_bfloat162 h; unsigned int u; } cvt;
    cvt.h = __float22bfloat162_rn(make_float2(a, b));
    return cvt.u;
}
__device__ __forceinline__ unsigned int fenc(float f) {
    unsigned int u = __float_as_uint(f);
    return (u & 0x80000000u) ? ~u : (u | 0x80000000u);
}
__device__ __forceinline__ float fdec(unsigned int u) {
    return __uint_as_float((u & 0x80000000u) ? (u & 0x7FFFFFFFu) : ~u);
}
__device__ __forceinline__ float gelu_fast(float x) {
    float x2 = x * x;
    float u = x * fmaf(0.0356774081f, x2, 0.7978845608f);
    float e = exp2f(u * -2.8853900818f);   // e^{-2u}
    float r = FRCP(e + 1.0f);              // sigma(2u)
    return x * r;
}
template<int CTRL>
__device__ __forceinline__ float dppadd(float s) {
    int v = __builtin_amdgcn_update_dpp(0, __float_as_int(s), CTRL, 0xF, 0xF, true);
    return s + __int_as_float(v);
}
__device__ __forceinline__ float rowsum16(float x) {
    x = dppadd<0x128>(x);   // ror:8
    x = dppadd<0x124>(x);   // ror:4
    x = dppadd<0x122>(x);   // ror:2
    x = dppadd<0x121>(x);   // ror:1
    return x;
}

// ---------------- K_prep ----------------------------------------------------
// blk 0..15 : w2T [n=256][k=256], k pi-permuted: pi(nt*16+lo)=lo*4+nt per 64-blk
// blk 16..19: w1aT [n=256][k=64]   (w1 rows 0..63, pf part)
// blk 20..27: w1cT [n=256][k=96]   (w1 rows 91..186, abs part)
// blk 28    : w1bT [n=256][k=32]   (w1 rows 64..90 rel part, pad 0)
// blk 29    : pooled_r init (8 replicas x 1024)
__global__ __launch_bounds__(256) void k_prep(
    const float* __restrict__ w1, const float* __restrict__ w2,
    unsigned short* __restrict__ w2T, unsigned short* __restrict__ w1aT,
    unsigned short* __restrict__ w1cT, unsigned short* __restrict__ w1bT,
    unsigned int* __restrict__ pooled_r)
{
    int t = threadIdx.x, blk = blockIdx.x;
    if (blk < 16) {                      // w2T: [n=256][k=256 permuted]
        __shared__ unsigned short tile[64][65];
        int tr = blk >> 2, tc = blk & 3;
        #pragma unroll
        for (int rr = 0; rr < 16; ++rr) {
            int kl = rr * 4 + (t >> 6), nl = t & 63;
            tile[kl][nl] = f2bf(w2[(size_t)(tr * 64 + kl) * 256 + tc * 64 + nl]);
        }
        __syncthreads();
        #pragma unroll
        for (int rr = 0; rr < 16; ++rr) {
            int nl = rr * 4 + (t >> 6), kp = t & 63;
            int kl = (kp & 3) * 16 + (kp >> 2);      // pi^-1
            w2T[(size_t)(tc * 64 + nl) * 256 + tr * 64 + kp] = tile[kl][nl];
        }
    } else if (blk < 20) {               // w1aT: [256][64]
        __shared__ unsigned short tile[64][65];
        int tc = blk - 16;
        #pragma unroll
        for (int rr = 0; rr < 16; ++rr) {
            int kl = rr * 4 + (t >> 6), nl = t & 63;
            tile[kl][nl] = f2bf(w1[(size_t)kl * 256 + tc * 64 + nl]);
        }
        __syncthreads();
        #pragma unroll
        for (int rr = 0; rr < 16; ++rr) {
            int nl = rr * 4 + (t >> 6), kl = t & 63;
            w1aT[(size_t)(tc * 64 + nl) * 64 + kl] = tile[kl][nl];
        }
    } else if (blk < 28) {               // w1cT: [256][96] from w1 rows 91..186
        __shared__ unsigned short tile[64][65];
        int idx = blk - 20;
        int tr2 = idx >> 2, tc = idx & 3;
        #pragma unroll
        for (int rr = 0; rr < 16; ++rr) {
            int kl = rr * 4 + (t >> 6), nl = t & 63;
            int k = tr2 * 64 + kl;
            float v = 0.f;
            if (k < 96) v = w1[(size_t)(91 + k) * 256 + tc * 64 + nl];
            tile[kl][nl] = f2bf(v);
        }
        __syncthreads();
        #pragma unroll
        for (int rr = 0; rr < 16; ++rr) {
            int nl = rr * 4 + (t >> 6), kl = t & 63;
            int k = tr2 * 64 + kl;
            if (k < 96)
                w1cT[(size_t)(tc * 64 + nl) * 96 + k] = tile[kl][nl];
        }
    } else if (blk == 28) {              // w1bT: [256][32], rel part
        int n = t;
        #pragma unroll
        for (int k = 0; k < 32; ++k) {
            unsigned short v = 0;
            if (k < 27) v = f2bf(w1[(size_t)(64 + k) * 256 + n]);
            w1bT[(size_t)n * 32 + k] = v;
        }
    } else {
        unsigned int idv = fenc(-1e19f);
        for (int q = t; q < 8192; q += 256) pooled_r[q] = idv;
    }
}

// ---------------- K_pre: U[p]=pf@w1a, V'[p]=absemb@w1c+b1 (pi-permuted f32) --
// 256 blocks x 256 threads; 64 rows/block; wave = 64 rows x 64 cols (wvN=wv)
__global__ __launch_bounds__(256) void k_pre(
    const float* __restrict__ xyz, const float* __restrict__ pf,
    const unsigned short* __restrict__ w1aT, const unsigned short* __restrict__ w1cT,
    const float* __restrict__ b1,
    float* __restrict__ U_p, float* __restrict__ V_p)
{
    __shared__ __align__(16) unsigned short ptile[64 * 72];    // pf bf16
    __shared__ __align__(16) unsigned short etile[64 * 104];   // abs emb bf16
    int tid = threadIdx.x, wv = tid >> 6, lane = tid & 63;
    int lo16 = lane & 15, quad = lane >> 4;
    int rows0 = blockIdx.x * 64;

    // stage pf (64 rows x 64 cols)
    {
        int r = tid >> 2, seg = tid & 3;
        const f32x4* src = (const f32x4*)(pf + (size_t)(rows0 + r) * 64 + seg * 16);
        f32x4 v0 = src[0], v1 = src[1], v2 = src[2], v3 = src[3];
        u32x4 o0, o1;
        o0.x = pack2(v0.x, v0.y); o0.y = pack2(v0.z, v0.w);
        o0.z = pack2(v1.x, v1.y); o0.w = pack2(v1.z, v1.w);
        o1.x = pack2(v2.x, v2.y); o1.y = pack2(v2.z, v2.w);
        o1.z = pack2(v3.x, v3.y); o1.w = pack2(v3.z, v3.w);
        u32x4* dst = (u32x4*)&ptile[r * 72 + seg * 16];
        dst[0] = o0; dst[1] = o1;
    }
    // stage abs sin-emb (64 rows x 96 cols = 48 pairs); freq=10000^(-jf/15)
    {
        int r = tid & 63, grp = tid >> 6;
        float c0 = xyz[(size_t)(rows0 + r) * 3];
        float c1 = xyz[(size_t)(rows0 + r) * 3 + 1];
        float c2 = xyz[(size_t)(rows0 + r) * 3 + 2];
        #pragma unroll
        for (int q = 0; q < 12; ++q) {
            int pr = grp * 12 + q;
            float vals[2];
            #pragma unroll
            for (int qq = 0; qq < 2; ++qq) {
                int cc = pr * 2 + qq;
                int a = cc >> 5, wI = cc & 31;
                int jf = (wI < 16) ? wI : (wI - 16);
                float coord = (a == 0) ? c0 : ((a == 1) ? c1 : c2);
                float fr = __expf(-0.61402269146507894f * (float)jf);
                float ang = coord * fr;
                vals[qq] = (wI < 16) ? __sinf(ang) : __cosf(ang);
            }
            *(unsigned int*)&etile[r * 104 + 2 * pr] = pack2(vals[0], vals[1]);
        }
    }
    __syncthreads();

    // U GEMM: K=64, C-init 0
    f32x4 acc[4][4];
    #pragma unroll
    for (int mt = 0; mt < 4; ++mt)
        #pragma unroll
        for (int nt = 0; nt < 4; ++nt) acc[mt][nt] = (f32x4){0.f, 0.f, 0.f, 0.f};
    #pragma unroll
    for (int ks = 0; ks < 2; ++ks) {
        bf16x8 bfr[4];
        #pragma unroll
        for (int nt = 0; nt < 4; ++nt) {
            int n = wv * 64 + nt * 16 + lo16;
            bfr[nt] = *(const bf16x8*)&w1aT[(size_t)n * 64 + ks * 32 + quad * 8];
        }
        #pragma unroll
        for (int mt = 0; mt < 4; ++mt) {
            bf16x8 afr = *(const bf16x8*)&ptile[(mt * 16 + lo16) * 72 + ks * 32 + quad * 8];
            #pragma unroll
            for (int nt = 0; nt < 4; ++nt)
                acc[mt][nt] = __builtin_amdgcn_mfma_f32_16x16x32_bf16(
                    afr, bfr[nt], acc[mt][nt], 0, 0, 0);
        }
    }
    #pragma unroll
    for (int mt = 0; mt < 4; ++mt)
        #pragma unroll
        for (int reg = 0; reg < 4; ++reg) {
            f32x4 o = {acc[mt][0][reg], acc[mt][1][reg], acc[mt][2][reg], acc[mt][3][reg]};
            *(f32x4*)&U_p[(size_t)(rows0 + mt * 16 + quad * 4 + reg) * 256 + wv * 64 + lo16 * 4] = o;
        }

    // V GEMM: K=96, C-init = b1 (folded)
    {
        float b1f[4];
        #pragma unroll
        for (int nt = 0; nt < 4; ++nt) b1f[nt] = b1[wv * 64 + nt * 16 + lo16];
        #pragma unroll
        for (int mt = 0; mt < 4; ++mt)
            #pragma unroll
            for (int nt = 0; nt < 4; ++nt)
                #pragma unroll
                for (int reg = 0; reg < 4; ++reg) acc[mt][nt][reg] = b1f[nt];
    }
    #pragma unroll
    for (int ks = 0; ks < 3; ++ks) {
        bf16x8 bfr[4];
        #pragma unroll
        for (int nt = 0; nt < 4; ++nt) {
            int n = wv * 64 + nt * 16 + lo16;
            bfr[nt] = *(const bf16x8*)&w1cT[(size_t)n * 96 + ks * 32 + quad * 8];
        }
        #pragma unroll
        for (int mt = 0; mt < 4; ++mt) {
            bf16x8 afr = *(const bf16x8*)&etile[(mt * 16 + lo16) * 104 + ks * 32 + quad * 8];
            #pragma unroll
            for (int nt = 0; nt < 4; ++nt)
                acc[mt][nt] = __builtin_amdgcn_mfma_f32_16x16x32_bf16(
                    afr, bfr[nt], acc[mt][nt], 0, 0, 0);
        }
    }
    #pragma unroll
    for (int mt = 0; mt < 4; ++mt)
        #pragma unroll
        for (int reg = 0; reg < 4; ++reg) {
            f32x4 o = {acc[mt][0][reg], acc[mt][1][reg], acc[mt][2][reg], acc[mt][3][reg]};
            *(f32x4*)&V_p[(size_t)(rows0 + mt * 16 + quad * 4 + reg) * 256 + wv * 64 + lo16 * 4] = o;
        }
}

// ---------------- K_main ---------------------------------------------------
__global__ __launch_bounds__(512, 4) void k_main(
    const float* __restrict__ xyz,
    const unsigned short* __restrict__ w1bT, const unsigned short* __restrict__ w2T,
    const float* __restrict__ U_p, const float* __restrict__ V_p,
    const float* __restrict__ g1, const float* __restrict__ be1,
    const float* __restrict__ b2, const float* __restrict__ g2,
    const float* __restrict__ be2,
    unsigned int* __restrict__ pooled_r)
{
    // rels (128 x 32+8, stride 40) unioned with h1s (128 x 256+8, stride 264)
    __shared__ __align__(16) unsigned short smem[128 * 264];   // 67584 B
    __shared__ unsigned long long bmask[4][64];
    __shared__ int   idxs[128];
    __shared__ float ctr[4][3];
    __shared__ float reds[128][4][2];
    __shared__ float musig[128][2];
    __shared__ unsigned int pool_s[256];
    unsigned short* rels = smem;  // stride 40 (dead once stage-1 MFMAs done)
    unsigned short* h1s  = smem;  // stride 264 (k-permuted within 64-blocks)

    const int N = 4096;
    int tid = threadIdx.x, wv = tid >> 6, lane = tid & 63;
    int lo16 = lane & 15, quad = lane >> 4;
    int wvM = wv >> 2, wvN = wv & 3;           // 2(M) x 4(N) wave grid
    int b = blockIdx.x & 3;                    // batch-major for L2 locality
    int i0 = (blockIdx.x >> 2) * 4;
    int rep = (blockIdx.x >> 2) & 7;           // pooled replica
    size_t base = (size_t)b * N;
    const float* xb = xyz + base * 3;

    // hoisted: rel-part stage-1 weights (independent of LDS)
    bf16x8 bfrR[4];
    #pragma unroll
    for (int nt = 0; nt < 4; ++nt) {
        int n = wvN * 64 + nt * 16 + lo16;
        bfrR[nt] = *(const bf16x8*)&w1bT[(size_t)n * 32 + quad * 8];
    }

    // P0a: centers + pool_s init
    if (tid < 256) pool_s[tid] = fenc(-1e19f);
    if (tid < 12) { int p = tid / 3, a = tid - 3 * p; ctr[p][a] = xb[(i0 + p) * 3 + a]; }
    // exact fp32 threshold: largest float <= (double)0.16*0.16  (validated R9)
    const double r2d = 0.16 * 0.16;
    float T = (float)r2d;
    if ((double)T > r2d) T = __uint_as_float(__float_as_uint(T) - 1u);
    // P0c phase A: each wave scans 8 chunks, all 4 centers per point load
    {
        f32x4 cA = *(const f32x4*)(xb + (size_t)i0 * 3);
        f32x4 cB = *(const f32x4*)(xb + (size_t)i0 * 3 + 4);
        f32x4 cC = *(const f32x4*)(xb + (size_t)i0 * 3 + 8);
        float cx0 = cA.x, cy0 = cA.y, cz0 = cA.z;
        float cx1 = cA.w, cy1 = cB.x, cz1 = cB.y;
        float cx2 = cB.z, cy2 = cB.w, cz2 = cC.x;
        float cx3 = cC.y, cy3 = cC.z, cz3 = cC.w;
        #pragma unroll 2
        for (int i = 0; i < 8; ++i) {
            int chunk = wv * 8 + i;
            int j = chunk * 64 + lane;
            const float* pp = xb + (size_t)j * 3;
            float px = pp[0], py = pp[1], pz = pp[2];
            float dx0 = __fsub_rn(px, cx0), dy0 = __fsub_rn(py, cy0), dz0 = __fsub_rn(pz, cz0);
            float sq0 = __fadd_rn(__fadd_rn(__fmul_rn(dx0, dx0), __fmul_rn(dy0, dy0)),
                                  __fmul_rn(dz0, dz0));
            unsigned long long m0 = __ballot(sq0 <= T);
            float dx1 = __fsub_rn(px, cx1), dy1 = __fsub_rn(py, cy1), dz1 = __fsub_rn(pz, cz1);
            float sq1 = __fadd_rn(__fadd_rn(__fmul_rn(dx1, dx1), __fmul_rn(dy1, dy1)),
                                  __fmul_rn(dz1, dz1));
            unsigned long long m1 = __ballot(sq1 <= T);
            float dx2 = __fsub_rn(px, cx2), dy2 = __fsub_rn(py, cy2), dz2 = __fsub_rn(pz, cz2);
            float sq2 = __fadd_rn(__fadd_rn(__fmul_rn(dx2, dx2), __fmul_rn(dy2, dy2)),
                                  __fmul_rn(dz2, dz2));
            unsigned long long m2 = __ballot(sq2 <= T);
            float dx3 = __fsub_rn(px, cx3), dy3 = __fsub_rn(py, cy3), dz3 = __fsub_rn(pz, cz3);
            float sq3 = __fadd_rn(__fadd_rn(__fmul_rn(dx3, dx3), __fmul_rn(dy3, dy3)),
                                  __fmul_rn(dz3, dz3));
            unsigned long long m3 = __ballot(sq3 <= T);
            if (lane == 0) {
                bmask[0][chunk] = m0; bmask[1][chunk] = m1;
                bmask[2][chunk] = m2; bmask[3][chunk] = m3;
            }
        }
    }
    __syncthreads();
    // P0c phase B: waves 0..3 select first 32 by ascending index (one center each)
    if (wv < 4) {
        int p = wv;
        unsigned long long m = bmask[p][lane];
        int c = __popcll(m);
        int inc = c;
        #pragma unroll
        for (int d = 1; d <= 32; d <<= 1) {
            int v = __shfl_up(inc, d);
            if (lane >= d) inc += v;
        }
        int exc = inc - c;
        int total = __shfl(inc, 63);
        unsigned long long lm = __ballot(m != 0ull);
        int fl = __ffsll(lm) - 1;                       // total>=1 (center in ball)
        unsigned long long mf = (unsigned long long)__shfl((long long)m, fl);
        int firstj = fl * 64 + __ffsll(mf) - 1;
        unsigned long long mm = m;
        int t = 0;
        while (mm != 0ull && (exc + t) < 32) {
            int bpos = __ffsll(mm) - 1;
            idxs[p * 32 + exc + t] = lane * 64 + bpos;
            mm &= mm - 1; ++t;
        }
        if (lane >= total && lane < 32) idxs[p * 32 + lane] = firstj;  // pad
    }
    __syncthreads();

    // P1b: rel xyz (cols 0..2) + rel emb (3..26) + zeros (27..31)
    {
        int r = tid & 127, part = tid >> 7;
        int p = r >> 5;
        int j = idxs[r];
        float rx = xb[j * 3]     - ctr[p][0];
        float ry = xb[j * 3 + 1] - ctr[p][1];
        float rz = xb[j * 3 + 2] - ctr[p][2];
        unsigned short* arow = &rels[r * 40];
        if (part == 0) {
            *(unsigned int*)&arow[0] = pack2(rx, ry);
            arow[2] = f2bf(rz);
            arow[27] = 0;
            *(u32x2*)&arow[28] = (u32x2){0u, 0u};
        } else {
            int a = part - 1;
            float cv = (a == 0) ? rx : ((a == 1) ? ry : rz);
            const float fr4[4] = {1.f, 0.046415888336127774f,
                                  0.0021544346900318843f, 1e-4f};  // 10000^(-j/3)
            float sn[4], cs[4];
            #pragma unroll
            for (int tt = 0; tt < 4; ++tt) {
                float ang = cv * fr4[tt];
                sn[tt] = __sinf(ang); cs[tt] = __cosf(ang);
            }
            arow[3 + a * 8 + 0] = f2bf(sn[0]); arow[3 + a * 8 + 1] = f2bf(sn[1]);
            arow[3 + a * 8 + 2] = f2bf(sn[2]); arow[3 + a * 8 + 3] = f2bf(sn[3]);
            arow[3 + a * 8 + 4] = f2bf(cs[0]); arow[3 + a * 8 + 5] = f2bf(cs[1]);
            arow[3 + a * 8 + 6] = f2bf(cs[2]); arow[3 + a * 8 + 7] = f2bf(cs[3]);
        }
    }
    __syncthreads();

    // P2: C-init = U[j] + V'[c]  (b1 folded into V'); then rel MFMA K=32
    const int arow0 = wvM * 64;
    f32x4 acc[4][4];
    #pragma unroll
    for (int mt = 0; mt < 4; ++mt) {
        int cl = wvM * 2 + (mt >> 1);   // center of rows [arow0+mt*16, +16)
        f32x4 vv = *(const f32x4*)&V_p[(size_t)(base + i0 + cl) * 256 + wvN * 64 + lo16 * 4];
        #pragma unroll
        for (int reg = 0; reg < 4; ++reg) {
            int r = arow0 + mt * 16 + quad * 4 + reg;
            int j = idxs[r];
            f32x4 uu = *(const f32x4*)&U_p[(size_t)(base + j) * 256 + wvN * 64 + lo16 * 4];
            #pragma unroll
            for (int nt = 0; nt < 4; ++nt) acc[mt][nt][reg] = uu[nt] + vv[nt];
        }
    }
    #pragma unroll
    for (int mt = 0; mt < 4; ++mt) {
        bf16x8 afr = *(const bf16x8*)&rels[(arow0 + mt * 16 + lo16) * 40 + quad * 8];
        #pragma unroll
        for (int nt = 0; nt < 4; ++nt)
            acc[mt][nt] = __builtin_amdgcn_mfma_f32_16x16x32_bf16(
                afr, bfrR[nt], acc[mt][nt], 0, 0, 0);
    }

    // P3: LN1 stats (DPP + cross-wave reds) -> gelu -> h1s (pi-packed b64)
    #pragma unroll
    for (int mt = 0; mt < 4; ++mt) {
        #pragma unroll
        for (int reg = 0; reg < 4; ++reg) {
            float s1 = 0.f, s2 = 0.f;
            #pragma unroll
            for (int nt = 0; nt < 4; ++nt) { float v = acc[mt][nt][reg]; s1 += v; s2 = fmaf(v, v, s2); }
            s1 = rowsum16(s1); s2 = rowsum16(s2);
            if (lo16 == 0) {
                int r = arow0 + mt * 16 + quad * 4 + reg;
                reds[r][wvN][0] = s1; reds[r][wvN][1] = s2;
            }
        }
    }
    __syncthreads();   // reds ready; all waves done reading rels
    if (tid < 128) {
        int r = tid;
        float s1 = reds[r][0][0] + reds[r][1][0] + reds[r][2][0] + reds[r][3][0];
        float s2 = reds[r][0][1] + reds[r][1][1] + reds[r][2][1] + reds[r][3][1];
        float mu = s1 * (1.f / 256.f);
        float var = fmaxf(s2 * (1.f / 256.f) - mu * mu, 0.f);
        musig[r][0] = mu; musig[r][1] = rsqrtf(var + LN_EPS);
    }
    __syncthreads();
    {
        float g1f[4], be1f[4];
        #pragma unroll
        for (int nt = 0; nt < 4; ++nt) {
            int n = wvN * 64 + nt * 16 + lo16;
            g1f[nt] = g1[n]; be1f[nt] = be1[n];
        }
        #pragma unroll
        for (int mt = 0; mt < 4; ++mt) {
            #pragma unroll
            for (int reg = 0; reg < 4; ++reg) {
                int r = arow0 + mt * 16 + quad * 4 + reg;
                float mu = musig[r][0], rs = musig[r][1];
                float v0 = gelu_fast(fmaf((acc[mt][0][reg] - mu) * rs, g1f[0], be1f[0]));
                float v1 = gelu_fast(fmaf((acc[mt][1][reg] - mu) * rs, g1f[1], be1f[1]));
                float v2 = gelu_fast(fmaf((acc[mt][2][reg] - mu) * rs, g1f[2], be1f[2]));
                float v3 = gelu_fast(fmaf((acc[mt][3][reg] - mu) * rs, g1f[3], be1f[3]));
                u32x2 w; w.x = pack2(v0, v1); w.y = pack2(v2, v3);
                *(u32x2*)&h1s[r * 264 + wvN * 64 + lo16 * 4] = w;   // pi(n)=lo16*4+nt
            }
        }
    }
    __syncthreads();   // h1s ready

    // P4: stage-2 MFMA K=256 (pi-permuted; w2T matches); C-init = b2
    {
        float b2f[4];
        #pragma unroll
        for (int nt = 0; nt < 4; ++nt) b2f[nt] = b2[wvN * 64 + nt * 16 + lo16];
        #pragma unroll
        for (int mt = 0; mt < 4; ++mt)
            #pragma unroll
            for (int nt = 0; nt < 4; ++nt)
                #pragma unroll
                for (int reg = 0; reg < 4; ++reg) acc[mt][nt][reg] = b2f[nt];
    }
    for (int ks = 0; ks < 8; ++ks) {
        bf16x8 bfr[4], afr[4];
        #pragma unroll
        for (int nt = 0; nt < 4; ++nt) {
            int n = wvN * 64 + nt * 16 + lo16;
            bfr[nt] = *(const bf16x8*)&w2T[(size_t)n * 256 + ks * 32 + quad * 8];
        }
        #pragma unroll
        for (int mt = 0; mt < 4; ++mt)
            afr[mt] = *(const bf16x8*)&h1s[(arow0 + mt * 16 + lo16) * 264 + ks * 32 + quad * 8];
        #pragma unroll
        for (int mt = 0; mt < 4; ++mt)
            #pragma unroll
            for (int nt = 0; nt < 4; ++nt)
                acc[mt][nt] = __builtin_amdgcn_mfma_f32_16x16x32_bf16(
                    afr[mt], bfr[nt], acc[mt][nt], 0, 0, 0);
    }

    // P5: LN2 stats (DPP + reds), normalize, col-max -> LDS pool_s -> global
    {
        #pragma unroll
        for (int mt = 0; mt < 4; ++mt) {
            #pragma unroll
            for (int reg = 0; reg < 4; ++reg) {
                float s1 = 0.f, s2 = 0.f;
                #pragma unroll
                for (int nt = 0; nt < 4; ++nt) { float v = acc[mt][nt][reg]; s1 += v; s2 = fmaf(v, v, s2); }
                s1 = rowsum16(s1); s2 = rowsum16(s2);
                if (lo16 == 0) {
                    int r = arow0 + mt * 16 + quad * 4 + reg;
                    reds[r][wvN][0] = s1; reds[r][wvN][1] = s2;
                }
            }
        }
        __syncthreads();
        if (tid < 128) {
            int r = tid;
            float s1 = reds[r][0][0] + reds[r][1][0] + reds[r][2][0] + reds[r][3][0];
            float s2 = reds[r][0][1] + reds[r][1][1] + reds[r][2][1] + reds[r][3][1];
            float mu = s1 * (1.f / 256.f);
            float var = fmaxf(s2 * (1.f / 256.f) - mu * mu, 0.f);
            musig[r][0] = mu; musig[r][1] = rsqrtf(var + LN_EPS);
        }
        __syncthreads();

        float g2f[4], be2f[4];
        #pragma unroll
        for (int nt = 0; nt < 4; ++nt) {
            int n = wvN * 64 + nt * 16 + lo16;
            g2f[nt] = g2[n]; be2f[nt] = be2[n];
        }
        float mx[4] = {-1e30f, -1e30f, -1e30f, -1e30f};
        #pragma unroll
        for (int mt = 0; mt < 4; ++mt) {
            #pragma unroll
            for (int reg = 0; reg < 4; ++reg) {
                int r = arow0 + mt * 16 + quad * 4 + reg;
                float mu = musig[r][0], rs = musig[r][1];
                #pragma unroll
                for (int nt = 0; nt < 4; ++nt) {
                    float v = fmaf((acc[mt][nt][reg] - mu) * rs, g2f[nt], be2f[nt]);
                    mx[nt] = fmaxf(mx[nt], v);
                }
            }
        }
        #pragma unroll
        for (int nt = 0; nt < 4; ++nt) {
            mx[nt] = fmaxf(mx[nt], __shfl_xor(mx[nt], 16));
            mx[nt] = fmaxf(mx[nt], __shfl_xor(mx[nt], 32));
        }
        if (quad == 0) {
            #pragma unroll
            for (int nt = 0; nt < 4; ++nt)
                atomicMax(&pool_s[wvN * 64 + nt * 16 + lo16], fenc(mx[nt]));
        }
    }
    // flush pool_s to this block's replica (256 coalesced atomics)
    __syncthreads();
    if (tid < 256)
        atomicMax(pooled_r + rep * 1024 + b * 256 + tid, pool_s[tid]);
}

// ---------------- K_final: replica max-reduce + final MLPs ------------------
__global__ __launch_bounds__(256) void k_final(
    const unsigned int* __restrict__ pooled_r,
    const float* __restrict__ pw1, const float* __restrict__ pb1,
    const float* __restrict__ pg1, const float* __restrict__ pbe1,
    const float* __restrict__ pw2, const float* __restrict__ pb2,
    const float* __restrict__ pg2, const float* __restrict__ pbe2,
    float* __restrict__ out)
{
    __shared__ float xw4[4][512];
    int tid = threadIdx.x, wv = tid >> 6, lane = tid & 63;
    int bb = wv;
    float* xw = xw4[wv];

    #pragma unroll
    for (int q = 0; q < 4; ++q) {
        int c = q * 64 + lane;
        unsigned int mv = pooled_r[bb * 256 + c];
        #pragma unroll
        for (int r = 1; r < 8; ++r) {
            unsigned int v = pooled_r[r * 1024 + bb * 256 + c];
            mv = (v > mv) ? v : mv;
        }
        xw[c] = fdec(mv);
    }

    float a1[4];
    #pragma unroll
    for (int q = 0; q < 4; ++q) a1[q] = pb1[q * 64 + lane];
    #pragma unroll 4
    for (int k = 0; k < 256; ++k) {
        float xv = xw[k];
        const float* wr = pw1 + (size_t)k * 256 + lane;
        #pragma unroll
        for (int q = 0; q < 4; ++q) a1[q] = fmaf(xv, wr[q * 64], a1[q]);
    }
    float s1 = a1[0] + a1[1] + a1[2] + a1[3];
    float s2 = fmaf(a1[0], a1[0], fmaf(a1[1], a1[1],
               fmaf(a1[2], a1[2], a1[3] * a1[3])));
    s1 = rowsum16(s1); s2 = rowsum16(s2);
    s1 += __shfl_xor(s1, 16); s2 += __shfl_xor(s2, 16);
    s1 += __shfl_xor(s1, 32); s2 += __shfl_xor(s2, 32);
    float mu = s1 * (1.f / 256.f);
    float rs = rsqrtf(fmaxf(s2 * (1.f / 256.f) - mu * mu, 0.f) + LN_EPS);
    #pragma unroll
    for (int q = 0; q < 4; ++q) {
        int c = q * 64 + lane;
        xw[256 + c] = gelu_fast(fmaf((a1[q] - mu) * rs, pg1[c], pbe1[c]));
    }

    float a2[4];
    #pragma unroll
    for (int q = 0; q < 4; ++q) a2[q] = pb2[q * 64 + lane];
    #pragma unroll 4
    for (int k = 0; k < 256; ++k) {
        float xv = xw[256 + k];
        const float* wr = pw2 + (size_t)k * 256 + lane;
        #pragma unroll
        for (int q = 0; q < 4; ++q) a2[q] = fmaf(xv, wr[q * 64], a2[q]);
    }
    s1 = a2[0] + a2[1] + a2[2] + a2[3];
    s2 = fmaf(a2[0], a2[0], fmaf(a2[1], a2[1],
         fmaf(a2[2], a2[2], a2[3] * a2[3])));
    s1 = rowsum16(s1); s2 = rowsum16(s2);
    s1 += __shfl_xor(s1, 16); s2 += __shfl_xor(s2, 16);
    s1 += __shfl_xor(s1, 32); s2 += __shfl_xor(s2, 32);
    mu = s1 * (1.f / 256.f);
    rs = rsqrtf(fmaxf(s2 * (1.f / 256.f) - mu * mu, 0.f) + LN_EPS);
    #pragma unroll
    for (int q = 0; q < 4; ++q) {
        int c = q * 64 + lane;
        out[bb * 256 + c] = fmaf((a2[q] - mu) * rs, pg2[c], pbe2[c]);
    }
}

// ---------------- launch ---------------------------------------------------
extern "C" void kernel_launch(void* const* d_in, const int* in_sizes, int n_in,
                              void* d_out, int out_size, void* d_ws, size_t ws_size,
                              hipStream_t stream)
{
    char* ws = (char*)d_ws;
    unsigned short* w2T      = (unsigned short*)ws;                      // 128 KB
    unsigned short* w1aT     = (unsigned short*)(ws + (128u << 10));     // 32 KB
    unsigned short* w1cT     = (unsigned short*)(ws + (160u << 10));     // 48 KB
    unsigned short* w1bT     = (unsigned short*)(ws + (208u << 10));     // 16 KB
    unsigned int*   pooled_r = (unsigned int*)(ws + (224u << 10));       // 32 KB
    float*          U_p      = (float*)(ws + (256u << 10));              // 16 MB
    float*          V_p      = (float*)(ws + (256u << 10) + (16u << 20)); // 16 MB

    const float* xyz = (const float*)d_in[0];
    const float* pf  = (const float*)d_in[1];
    const float* w1  = (const float*)d_in[2];
    const float* b1  = (const float*)d_in[3];

    k_prep<<<30, 256, 0, stream>>>(w1, (const float*)d_in[6],
                                   w2T, w1aT, w1cT, w1bT, pooled_r);
    k_pre<<<256, 256, 0, stream>>>(xyz, pf, w1aT, w1cT, b1, U_p, V_p);
    k_main<<<4096, 512, 0, stream>>>(xyz, w1bT, w2T, U_p, V_p,
                                     (const float*)d_in[4], (const float*)d_in[5],
                                     (const float*)d_in[7], (const float*)d_in[8],
                                     (const float*)d_in[9], pooled_r);
    k_final<<<1, 256, 0, stream>>>(pooled_r,
                                   (const float*)d_in[10], (const float*)d_in[11],
                                   (const float*)d_in[12], (const float*)d_in[13],
                                   (const float*)d_in[14], (const float*)d_in[15],
                                   (const float*)d_in[16], (const float*)d_in[17],
                                   (float*)d_out);
}

// Round 6
// 384.789 us; speedup vs baseline: 2.6133x; 1.0448x over previous
//
#include <hip/hip_runtime.h>
#include <hip/hip_bf16.h>
#include <math.h>

// GlobalSceneTokenizer fused pipeline, f32 in/out.
// R20 = R19 + serial-tail removal. R19 measured: k_main 289us but total 402
// -> 113us in k_pre (1 blk/CU latency-exposed) + k_final (1 block serial) +
// gaps. This round: (1) k_pre 256->1024 blocks (16 rows/blk, 6 trig/thread,
// ~16 waves/CU); (2) k_final 4 blocks, thread-per-column coalesced loops;
// (3) pooled replicas 8->32 (128KB) -> 4x less atomic line bouncing
// (k_main WRITE_SIZE 53MB -> ~25MB predicted).
// k_main dataflow unchanged from R19 (= R18 factored stage-1: U[j]=pf@w1a,
// V'[c]=absemb@w1c+b1 precomputed; stage-1 = C-init gather(U)+V' + one K=32
// rel MFMA; stage-2 K=256 pi-permuted; 128 rows, 8 waves 2Mx4N).

#define LN_EPS 1e-5f

typedef __attribute__((ext_vector_type(8))) short bf16x8;
typedef __attribute__((ext_vector_type(4))) float f32x4;
typedef __attribute__((ext_vector_type(2))) unsigned int u32x2;
typedef __attribute__((ext_vector_type(4))) unsigned int u32x4;

#if __has_builtin(__builtin_amdgcn_rcpf)
#define FRCP(x) __builtin_amdgcn_rcpf(x)
#else
#define FRCP(x) (1.0f / (x))
#endif

__device__ __forceinline__ unsigned short f2bf(float f) {
    unsigned int x = __float_as_uint(f);
    return (unsigned short)((x + 0x7FFFu + ((x >> 16) & 1u)) >> 16);  // RNE
}
__device__ __forceinline__ unsigned int pack2(float a, float b) {
    union { __hip_bfloat162 h; unsigned int u; } cvt;
    cvt.h = __float22bfloat162_rn(make_float2(a, b));
    return cvt.u;
}
__device__ __forceinline__ unsigned int fenc(float f) {
    unsigned int u = __float_as_uint(f);
    return (u & 0x80000000u) ? ~u : (u | 0x80000000u);
}
__device__ __forceinline__ float fdec(unsigned int u) {
    return __uint_as_float((u & 0x80000000u) ? (u & 0x7FFFFFFFu) : ~u);
}
__device__ __forceinline__ float gelu_fast(float x) {
    float x2 = x * x;
    float u = x * fmaf(0.0356774081f, x2, 0.7978845608f);
    float e = exp2f(u * -2.8853900818f);   // e^{-2u}
    float r = FRCP(e + 1.0f);              // sigma(2u)
    return x * r;
}
template<int CTRL>
__device__ __forceinline__ float dppadd(float s) {
    int v = __builtin_amdgcn_update_dpp(0, __float_as_int(s), CTRL, 0xF, 0xF, true);
    return s + __int_as_float(v);
}
__device__ __forceinline__ float rowsum16(float x) {
    x = dppadd<0x128>(x);   // ror:8
    x = dppadd<0x124>(x);   // ror:4
    x = dppadd<0x122>(x);   // ror:2
    x = dppadd<0x121>(x);   // ror:1
    return x;
}

// ---------------- K_prep ----------------------------------------------------
// blk 0..15 : w2T [n=256][k=256], k pi-permuted: pi(nt*16+lo)=lo*4+nt per 64-blk
// blk 16..19: w1aT [n=256][k=64]   (w1 rows 0..63, pf part)
// blk 20..27: w1cT [n=256][k=96]   (w1 rows 91..186, abs part)
// blk 28    : w1bT [n=256][k=32]   (w1 rows 64..90 rel part, pad 0)
// blk 29    : pooled_r init (32 replicas x 1024)
__global__ __launch_bounds__(256) void k_prep(
    const float* __restrict__ w1, const float* __restrict__ w2,
    unsigned short* __restrict__ w2T, unsigned short* __restrict__ w1aT,
    unsigned short* __restrict__ w1cT, unsigned short* __restrict__ w1bT,
    unsigned int* __restrict__ pooled_r)
{
    int t = threadIdx.x, blk = blockIdx.x;
    if (blk < 16) {                      // w2T: [n=256][k=256 permuted]
        __shared__ unsigned short tile[64][65];
        int tr = blk >> 2, tc = blk & 3;
        #pragma unroll
        for (int rr = 0; rr < 16; ++rr) {
            int kl = rr * 4 + (t >> 6), nl = t & 63;
            tile[kl][nl] = f2bf(w2[(size_t)(tr * 64 + kl) * 256 + tc * 64 + nl]);
        }
        __syncthreads();
        #pragma unroll
        for (int rr = 0; rr < 16; ++rr) {
            int nl = rr * 4 + (t >> 6), kp = t & 63;
            int kl = (kp & 3) * 16 + (kp >> 2);      // pi^-1
            w2T[(size_t)(tc * 64 + nl) * 256 + tr * 64 + kp] = tile[kl][nl];
        }
    } else if (blk < 20) {               // w1aT: [256][64]
        __shared__ unsigned short tile[64][65];
        int tc = blk - 16;
        #pragma unroll
        for (int rr = 0; rr < 16; ++rr) {
            int kl = rr * 4 + (t >> 6), nl = t & 63;
            tile[kl][nl] = f2bf(w1[(size_t)kl * 256 + tc * 64 + nl]);
        }
        __syncthreads();
        #pragma unroll
        for (int rr = 0; rr < 16; ++rr) {
            int nl = rr * 4 + (t >> 6), kl = t & 63;
            w1aT[(size_t)(tc * 64 + nl) * 64 + kl] = tile[kl][nl];
        }
    } else if (blk < 28) {               // w1cT: [256][96] from w1 rows 91..186
        __shared__ unsigned short tile[64][65];
        int idx = blk - 20;
        int tr2 = idx >> 2, tc = idx & 3;
        #pragma unroll
        for (int rr = 0; rr < 16; ++rr) {
            int kl = rr * 4 + (t >> 6), nl = t & 63;
            int k = tr2 * 64 + kl;
            float v = 0.f;
            if (k < 96) v = w1[(size_t)(91 + k) * 256 + tc * 64 + nl];
            tile[kl][nl] = f2bf(v);
        }
        __syncthreads();
        #pragma unroll
        for (int rr = 0; rr < 16; ++rr) {
            int nl = rr * 4 + (t >> 6), kl = t & 63;
            int k = tr2 * 64 + kl;
            if (k < 96)
                w1cT[(size_t)(tc * 64 + nl) * 96 + k] = tile[kl][nl];
        }
    } else if (blk == 28) {              // w1bT: [256][32], rel part
        int n = t;
        #pragma unroll
        for (int k = 0; k < 32; ++k) {
            unsigned short v = 0;
            if (k < 27) v = f2bf(w1[(size_t)(64 + k) * 256 + n]);
            w1bT[(size_t)n * 32 + k] = v;
        }
    } else {
        unsigned int idv = fenc(-1e19f);
        for (int q = t; q < 32768; q += 256) pooled_r[q] = idv;
    }
}

// ---------------- K_pre: U[p]=pf@w1a, V'[p]=absemb@w1c+b1 (pi-permuted f32) --
// 1024 blocks x 256 threads; 16 rows/block; wave = 16 rows x 64 cols (wvN=wv)
__global__ __launch_bounds__(256) void k_pre(
    const float* __restrict__ xyz, const float* __restrict__ pf,
    const unsigned short* __restrict__ w1aT, const unsigned short* __restrict__ w1cT,
    const float* __restrict__ b1,
    float* __restrict__ U_p, float* __restrict__ V_p)
{
    __shared__ __align__(16) unsigned short ptile[16 * 72];    // pf bf16
    __shared__ __align__(16) unsigned short etile[16 * 104];   // abs emb bf16
    int tid = threadIdx.x, wv = tid >> 6, lane = tid & 63;
    int lo16 = lane & 15, quad = lane >> 4;
    int rows0 = blockIdx.x * 16;

    // stage pf (16 rows x 64 cols): thread = (row, 4-float seg)
    {
        int r = tid >> 4, seg = tid & 15;
        f32x4 v = *(const f32x4*)(pf + (size_t)(rows0 + r) * 64 + seg * 4);
        u32x2 o; o.x = pack2(v.x, v.y); o.y = pack2(v.z, v.w);
        *(u32x2*)&ptile[r * 72 + seg * 4] = o;
    }
    // stage abs sin-emb (16 rows x 48 pairs = 768 items); 3 items/thread
    #pragma unroll
    for (int q = 0; q < 3; ++q) {
        int item = q * 256 + tid;
        int r = item / 48, pr = item - 48 * r;
        float vals[2];
        #pragma unroll
        for (int qq = 0; qq < 2; ++qq) {
            int cc = pr * 2 + qq;
            int a = cc >> 5, wI = cc & 31;
            int jf = (wI < 16) ? wI : (wI - 16);
            float coord = xyz[(size_t)(rows0 + r) * 3 + a];
            float fr = __expf(-0.61402269146507894f * (float)jf);
            float ang = coord * fr;
            vals[qq] = (wI < 16) ? __sinf(ang) : __cosf(ang);
        }
        *(unsigned int*)&etile[r * 104 + 2 * pr] = pack2(vals[0], vals[1]);
    }
    __syncthreads();

    // U GEMM: K=64, C-init 0; wave covers cols wv*64..+64 of its 16 rows
    f32x4 acc[4];
    #pragma unroll
    for (int nt = 0; nt < 4; ++nt) acc[nt] = (f32x4){0.f, 0.f, 0.f, 0.f};
    #pragma unroll
    for (int ks = 0; ks < 2; ++ks) {
        bf16x8 afr = *(const bf16x8*)&ptile[lo16 * 72 + ks * 32 + quad * 8];
        #pragma unroll
        for (int nt = 0; nt < 4; ++nt) {
            int n = wv * 64 + nt * 16 + lo16;
            bf16x8 bfr = *(const bf16x8*)&w1aT[(size_t)n * 64 + ks * 32 + quad * 8];
            acc[nt] = __builtin_amdgcn_mfma_f32_16x16x32_bf16(afr, bfr, acc[nt], 0, 0, 0);
        }
    }
    #pragma unroll
    for (int reg = 0; reg < 4; ++reg) {
        f32x4 o = {acc[0][reg], acc[1][reg], acc[2][reg], acc[3][reg]};
        *(f32x4*)&U_p[(size_t)(rows0 + quad * 4 + reg) * 256 + wv * 64 + lo16 * 4] = o;
    }

    // V GEMM: K=96, C-init = b1 (folded)
    {
        float b1f[4];
        #pragma unroll
        for (int nt = 0; nt < 4; ++nt) b1f[nt] = b1[wv * 64 + nt * 16 + lo16];
        #pragma unroll
        for (int nt = 0; nt < 4; ++nt)
            #pragma unroll
            for (int reg = 0; reg < 4; ++reg) acc[nt][reg] = b1f[nt];
    }
    #pragma unroll
    for (int ks = 0; ks < 3; ++ks) {
        bf16x8 afr = *(const bf16x8*)&etile[lo16 * 104 + ks * 32 + quad * 8];
        #pragma unroll
        for (int nt = 0; nt < 4; ++nt) {
            int n = wv * 64 + nt * 16 + lo16;
            bf16x8 bfr = *(const bf16x8*)&w1cT[(size_t)n * 96 + ks * 32 + quad * 8];
            acc[nt] = __builtin_amdgcn_mfma_f32_16x16x32_bf16(afr, bfr, acc[nt], 0, 0, 0);
        }
    }
    #pragma unroll
    for (int reg = 0; reg < 4; ++reg) {
        f32x4 o = {acc[0][reg], acc[1][reg], acc[2][reg], acc[3][reg]};
        *(f32x4*)&V_p[(size_t)(rows0 + quad * 4 + reg) * 256 + wv * 64 + lo16 * 4] = o;
    }
}

// ---------------- K_main ---------------------------------------------------
__global__ __launch_bounds__(512, 4) void k_main(
    const float* __restrict__ xyz,
    const unsigned short* __restrict__ w1bT, const unsigned short* __restrict__ w2T,
    const float* __restrict__ U_p, const float* __restrict__ V_p,
    const float* __restrict__ g1, const float* __restrict__ be1,
    const float* __restrict__ b2, const float* __restrict__ g2,
    const float* __restrict__ be2,
    unsigned int* __restrict__ pooled_r)
{
    // rels (128 x 32+8, stride 40) unioned with h1s (128 x 256+8, stride 264)
    __shared__ __align__(16) unsigned short smem[128 * 264];   // 67584 B
    __shared__ unsigned long long bmask[4][64];
    __shared__ int   idxs[128];
    __shared__ float ctr[4][3];
    __shared__ float reds[128][4][2];
    __shared__ float musig[128][2];
    __shared__ unsigned int pool_s[256];
    unsigned short* rels = smem;  // stride 40 (dead once stage-1 MFMAs done)
    unsigned short* h1s  = smem;  // stride 264 (k-permuted within 64-blocks)

    const int N = 4096;
    int tid = threadIdx.x, wv = tid >> 6, lane = tid & 63;
    int lo16 = lane & 15, quad = lane >> 4;
    int wvM = wv >> 2, wvN = wv & 3;           // 2(M) x 4(N) wave grid
    int b = blockIdx.x & 3;                    // batch-major for L2 locality
    int i0 = (blockIdx.x >> 2) * 4;
    int rep = (blockIdx.x >> 2) & 31;          // pooled replica
    size_t base = (size_t)b * N;
    const float* xb = xyz + base * 3;

    // hoisted: rel-part stage-1 weights (independent of LDS)
    bf16x8 bfrR[4];
    #pragma unroll
    for (int nt = 0; nt < 4; ++nt) {
        int n = wvN * 64 + nt * 16 + lo16;
        bfrR[nt] = *(const bf16x8*)&w1bT[(size_t)n * 32 + quad * 8];
    }

    // P0a: centers + pool_s init
    if (tid < 256) pool_s[tid] = fenc(-1e19f);
    if (tid < 12) { int p = tid / 3, a = tid - 3 * p; ctr[p][a] = xb[(i0 + p) * 3 + a]; }
    // exact fp32 threshold: largest float <= (double)0.16*0.16  (validated R9)
    const double r2d = 0.16 * 0.16;
    float T = (float)r2d;
    if ((double)T > r2d) T = __uint_as_float(__float_as_uint(T) - 1u);
    // P0c phase A: each wave scans 8 chunks, all 4 centers per point load
    {
        f32x4 cA = *(const f32x4*)(xb + (size_t)i0 * 3);
        f32x4 cB = *(const f32x4*)(xb + (size_t)i0 * 3 + 4);
        f32x4 cC = *(const f32x4*)(xb + (size_t)i0 * 3 + 8);
        float cx0 = cA.x, cy0 = cA.y, cz0 = cA.z;
        float cx1 = cA.w, cy1 = cB.x, cz1 = cB.y;
        float cx2 = cB.z, cy2 = cB.w, cz2 = cC.x;
        float cx3 = cC.y, cy3 = cC.z, cz3 = cC.w;
        #pragma unroll 2
        for (int i = 0; i < 8; ++i) {
            int chunk = wv * 8 + i;
            int j = chunk * 64 + lane;
            const float* pp = xb + (size_t)j * 3;
            float px = pp[0], py = pp[1], pz = pp[2];
            float dx0 = __fsub_rn(px, cx0), dy0 = __fsub_rn(py, cy0), dz0 = __fsub_rn(pz, cz0);
            float sq0 = __fadd_rn(__fadd_rn(__fmul_rn(dx0, dx0), __fmul_rn(dy0, dy0)),
                                  __fmul_rn(dz0, dz0));
            unsigned long long m0 = __ballot(sq0 <= T);
            float dx1 = __fsub_rn(px, cx1), dy1 = __fsub_rn(py, cy1), dz1 = __fsub_rn(pz, cz1);
            float sq1 = __fadd_rn(__fadd_rn(__fmul_rn(dx1, dx1), __fmul_rn(dy1, dy1)),
                                  __fmul_rn(dz1, dz1));
            unsigned long long m1 = __ballot(sq1 <= T);
            float dx2 = __fsub_rn(px, cx2), dy2 = __fsub_rn(py, cy2), dz2 = __fsub_rn(pz, cz2);
            float sq2 = __fadd_rn(__fadd_rn(__fmul_rn(dx2, dx2), __fmul_rn(dy2, dy2)),
                                  __fmul_rn(dz2, dz2));
            unsigned long long m2 = __ballot(sq2 <= T);
            float dx3 = __fsub_rn(px, cx3), dy3 = __fsub_rn(py, cy3), dz3 = __fsub_rn(pz, cz3);
            float sq3 = __fadd_rn(__fadd_rn(__fmul_rn(dx3, dx3), __fmul_rn(dy3, dy3)),
                                  __fmul_rn(dz3, dz3));
            unsigned long long m3 = __ballot(sq3 <= T);
            if (lane == 0) {
                bmask[0][chunk] = m0; bmask[1][chunk] = m1;
                bmask[2][chunk] = m2; bmask[3][chunk] = m3;
            }
        }
    }
    __syncthreads();
    // P0c phase B: waves 0..3 select first 32 by ascending index (one center each)
    if (wv < 4) {
        int p = wv;
        unsigned long long m = bmask[p][lane];
        int c = __popcll(m);
        int inc = c;
        #pragma unroll
        for (int d = 1; d <= 32; d <<= 1) {
            int v = __shfl_up(inc, d);
            if (lane >= d) inc += v;
        }
        int exc = inc - c;
        int total = __shfl(inc, 63);
        unsigned long long lm = __ballot(m != 0ull);
        int fl = __ffsll(lm) - 1;                       // total>=1 (center in ball)
        unsigned long long mf = (unsigned long long)__shfl((long long)m, fl);
        int firstj = fl * 64 + __ffsll(mf) - 1;
        unsigned long long mm = m;
        int t = 0;
        while (mm != 0ull && (exc + t) < 32) {
            int bpos = __ffsll(mm) - 1;
            idxs[p * 32 + exc + t] = lane * 64 + bpos;
            mm &= mm - 1; ++t;
        }
        if (lane >= total && lane < 32) idxs[p * 32 + lane] = firstj;  // pad
    }
    __syncthreads();

    // P1b: rel xyz (cols 0..2) + rel emb (3..26) + zeros (27..31)
    {
        int r = tid & 127, part = tid >> 7;
        int p = r >> 5;
        int j = idxs[r];
        float rx = xb[j * 3]     - ctr[p][0];
        float ry = xb[j * 3 + 1] - ctr[p][1];
        float rz = xb[j * 3 + 2] - ctr[p][2];
        unsigned short* arow = &rels[r * 40];
        if (part == 0) {
            *(unsigned int*)&arow[0] = pack2(rx, ry);
            arow[2] = f2bf(rz);
            arow[27] = 0;
            *(u32x2*)&arow[28] = (u32x2){0u, 0u};
        } else {
            int a = part - 1;
            float cv = (a == 0) ? rx : ((a == 1) ? ry : rz);
            const float fr4[4] = {1.f, 0.046415888336127774f,
                                  0.0021544346900318843f, 1e-4f};  // 10000^(-j/3)
            float sn[4], cs[4];
            #pragma unroll
            for (int tt = 0; tt < 4; ++tt) {
                float ang = cv * fr4[tt];
                sn[tt] = __sinf(ang); cs[tt] = __cosf(ang);
            }
            arow[3 + a * 8 + 0] = f2bf(sn[0]); arow[3 + a * 8 + 1] = f2bf(sn[1]);
            arow[3 + a * 8 + 2] = f2bf(sn[2]); arow[3 + a * 8 + 3] = f2bf(sn[3]);
            arow[3 + a * 8 + 4] = f2bf(cs[0]); arow[3 + a * 8 + 5] = f2bf(cs[1]);
            arow[3 + a * 8 + 6] = f2bf(cs[2]); arow[3 + a * 8 + 7] = f2bf(cs[3]);
        }
    }
    __syncthreads();

    // P2: C-init = U[j] + V'[c]  (b1 folded into V'); then rel MFMA K=32
    const int arow0 = wvM * 64;
    f32x4 acc[4][4];
    #pragma unroll
    for (int mt = 0; mt < 4; ++mt) {
        int cl = wvM * 2 + (mt >> 1);   // center of rows [arow0+mt*16, +16)
        f32x4 vv = *(const f32x4*)&V_p[(size_t)(base + i0 + cl) * 256 + wvN * 64 + lo16 * 4];
        #pragma unroll
        for (int reg = 0; reg < 4; ++reg) {
            int r = arow0 + mt * 16 + quad * 4 + reg;
            int j = idxs[r];
            f32x4 uu = *(const f32x4*)&U_p[(size_t)(base + j) * 256 + wvN * 64 + lo16 * 4];
            #pragma unroll
            for (int nt = 0; nt < 4; ++nt) acc[mt][nt][reg] = uu[nt] + vv[nt];
        }
    }
    #pragma unroll
    for (int mt = 0; mt < 4; ++mt) {
        bf16x8 afr = *(const bf16x8*)&rels[(arow0 + mt * 16 + lo16) * 40 + quad * 8];
        #pragma unroll
        for (int nt = 0; nt < 4; ++nt)
            acc[mt][nt] = __builtin_amdgcn_mfma_f32_16x16x32_bf16(
                afr, bfrR[nt], acc[mt][nt], 0, 0, 0);
    }

    // P3: LN1 stats (DPP + cross-wave reds) -> gelu -> h1s (pi-packed b64)
    #pragma unroll
    for (int mt = 0; mt < 4; ++mt) {
        #pragma unroll
        for (int reg = 0; reg < 4; ++reg) {
            float s1 = 0.f, s2 = 0.f;
            #pragma unroll
            for (int nt = 0; nt < 4; ++nt) { float v = acc[mt][nt][reg]; s1 += v; s2 = fmaf(v, v, s2); }
            s1 = rowsum16(s1); s2 = rowsum16(s2);
            if (lo16 == 0) {
                int r = arow0 + mt * 16 + quad * 4 + reg;
                reds[r][wvN][0] = s1; reds[r][wvN][1] = s2;
            }
        }
    }
    __syncthreads();   // reds ready; all waves done reading rels
    if (tid < 128) {
        int r = tid;
        float s1 = reds[r][0][0] + reds[r][1][0] + reds[r][2][0] + reds[r][3][0];
        float s2 = reds[r][0][1] + reds[r][1][1] + reds[r][2][1] + reds[r][3][1];
        float mu = s1 * (1.f / 256.f);
        float var = fmaxf(s2 * (1.f / 256.f) - mu * mu, 0.f);
        musig[r][0] = mu; musig[r][1] = rsqrtf(var + LN_EPS);
    }
    __syncthreads();
    {
        float g1f[4], be1f[4];
        #pragma unroll
        for (int nt = 0; nt < 4; ++nt) {
            int n = wvN * 64 + nt * 16 + lo16;
            g1f[nt] = g1[n]; be1f[nt] = be1[n];
        }
        #pragma unroll
        for (int mt = 0; mt < 4; ++mt) {
            #pragma unroll
            for (int reg = 0; reg < 4; ++reg) {
                int r = arow0 + mt * 16 + quad * 4 + reg;
                float mu = musig[r][0], rs = musig[r][1];
                float v0 = gelu_fast(fmaf((acc[mt][0][reg] - mu) * rs, g1f[0], be1f[0]));
                float v1 = gelu_fast(fmaf((acc[mt][1][reg] - mu) * rs, g1f[1], be1f[1]));
                float v2 = gelu_fast(fmaf((acc[mt][2][reg] - mu) * rs, g1f[2], be1f[2]));
                float v3 = gelu_fast(fmaf((acc[mt][3][reg] - mu) * rs, g1f[3], be1f[3]));
                u32x2 w; w.x = pack2(v0, v1); w.y = pack2(v2, v3);
                *(u32x2*)&h1s[r * 264 + wvN * 64 + lo16 * 4] = w;   // pi(n)=lo16*4+nt
            }
        }
    }
    __syncthreads();   // h1s ready

    // P4: stage-2 MFMA K=256 (pi-permuted; w2T matches); C-init = b2
    {
        float b2f[4];
        #pragma unroll
        for (int nt = 0; nt < 4; ++nt) b2f[nt] = b2[wvN * 64 + nt * 16 + lo16];
        #pragma unroll
        for (int mt = 0; mt < 4; ++mt)
            #pragma unroll
            for (int nt = 0; nt < 4; ++nt)
                #pragma unroll
                for (int reg = 0; reg < 4; ++reg) acc[mt][nt][reg] = b2f[nt];
    }
    for (int ks = 0; ks < 8; ++ks) {
        bf16x8 bfr[4], afr[4];
        #pragma unroll
        for (int nt = 0; nt < 4; ++nt) {
            int n = wvN * 64 + nt * 16 + lo16;
            bfr[nt] = *(const bf16x8*)&w2T[(size_t)n * 256 + ks * 32 + quad * 8];
        }
        #pragma unroll
        for (int mt = 0; mt < 4; ++mt)
            afr[mt] = *(const bf16x8*)&h1s[(arow0 + mt * 16 + lo16) * 264 + ks * 32 + quad * 8];
        #pragma unroll
        for (int mt = 0; mt < 4; ++mt)
            #pragma unroll
            for (int nt = 0; nt < 4; ++nt)
                acc[mt][nt] = __builtin_amdgcn_mfma_f32_16x16x32_bf16(
                    afr[mt], bfr[nt], acc[mt][nt], 0, 0, 0);
    }

    // P5: LN2 stats (DPP + reds), normalize, col-max -> LDS pool_s -> global
    {
        #pragma unroll
        for (int mt = 0; mt < 4; ++mt) {
            #pragma unroll
            for (int reg = 0; reg < 4; ++reg) {
                float s1 = 0.f, s2 = 0.f;
                #pragma unroll
                for (int nt = 0; nt < 4; ++nt) { float v = acc[mt][nt][reg]; s1 += v; s2 = fmaf(v, v, s2); }
                s1 = rowsum16(s1); s2 = rowsum16(s2);
                if (lo16 == 0) {
                    int r = arow0 + mt * 16 + quad * 4 + reg;
                    reds[r][wvN][0] = s1; reds[r][wvN][1] = s2;
                }
            }
        }
        __syncthreads();
        if (tid < 128) {
            int r = tid;
            float s1 = reds[r][0][0] + reds[r][1][0] + reds[r][2][0] + reds[r][3][0];
            float s2 = reds[r][0][1] + reds[r][1][1] + reds[r][2][1] + reds[r][3][1];
            float mu = s1 * (1.f / 256.f);
            float var = fmaxf(s2 * (1.f / 256.f) - mu * mu, 0.f);
            musig[r][0] = mu; musig[r][1] = rsqrtf(var + LN_EPS);
        }
        __syncthreads();

        float g2f[4], be2f[4];
        #pragma unroll
        for (int nt = 0; nt < 4; ++nt) {
            int n = wvN * 64 + nt * 16 + lo16;
            g2f[nt] = g2[n]; be2f[nt] = be2[n];
        }
        float mx[4] = {-1e30f, -1e30f, -1e30f, -1e30f};
        #pragma unroll
        for (int mt = 0; mt < 4; ++mt) {
            #pragma unroll
            for (int reg = 0; reg < 4; ++reg) {
                int r = arow0 + mt * 16 + quad * 4 + reg;
                float mu = musig[r][0], rs = musig[r][1];
                #pragma unroll
                for (int nt = 0; nt < 4; ++nt) {
                    float v = fmaf((acc[mt][nt][reg] - mu) * rs, g2f[nt], be2f[nt]);
                    mx[nt] = fmaxf(mx[nt], v);
                }
            }
        }
        #pragma unroll
        for (int nt = 0; nt < 4; ++nt) {
            mx[nt] = fmaxf(mx[nt], __shfl_xor(mx[nt], 16));
            mx[nt] = fmaxf(mx[nt], __shfl_xor(mx[nt], 32));
        }
        if (quad == 0) {
            #pragma unroll
            for (int nt = 0; nt < 4; ++nt)
                atomicMax(&pool_s[wvN * 64 + nt * 16 + lo16], fenc(mx[nt]));
        }
    }
    // flush pool_s to this block's replica (256 coalesced atomics)
    __syncthreads();
    if (tid < 256)
        atomicMax(pooled_r + rep * 1024 + b * 256 + tid, pool_s[tid]);
}

// ---------------- K_final: replica max-reduce + final MLPs ------------------
// 4 blocks (one per batch) x 256 threads; thread owns output col c = tid.
__global__ __launch_bounds__(256) void k_final(
    const unsigned int* __restrict__ pooled_r,
    const float* __restrict__ pw1, const float* __restrict__ pb1,
    const float* __restrict__ pg1, const float* __restrict__ pbe1,
    const float* __restrict__ pw2, const float* __restrict__ pb2,
    const float* __restrict__ pg2, const float* __restrict__ pbe2,
    float* __restrict__ out)
{
    __shared__ float xw[256], xh[256];
    __shared__ float lred[2][4];
    int tid = threadIdx.x, wv = tid >> 6;
    int bb = blockIdx.x;

    // replica max-reduce for this thread's column
    {
        unsigned int mv = pooled_r[bb * 256 + tid];
        #pragma unroll
        for (int r = 1; r < 32; ++r) {
            unsigned int v = pooled_r[r * 1024 + bb * 256 + tid];
            mv = (v > mv) ? v : mv;
        }
        xw[tid] = fdec(mv);
    }
    __syncthreads();

    // MLP1: a1[c] = pb1[c] + sum_k xw[k]*pw1[k][c]
    float a1 = pb1[tid];
    #pragma unroll 8
    for (int k = 0; k < 256; ++k)
        a1 = fmaf(xw[k], pw1[(size_t)k * 256 + tid], a1);
    // LN over cols (4-wave reduce)
    float s1 = a1, s2 = a1 * a1;
    s1 = rowsum16(s1); s2 = rowsum16(s2);
    s1 += __shfl_xor(s1, 16); s2 += __shfl_xor(s2, 16);
    s1 += __shfl_xor(s1, 32); s2 += __shfl_xor(s2, 32);
    if ((tid & 63) == 0) { lred[0][wv] = s1; lred[1][wv] = s2; }
    __syncthreads();
    s1 = lred[0][0] + lred[0][1] + lred[0][2] + lred[0][3];
    s2 = lred[1][0] + lred[1][1] + lred[1][2] + lred[1][3];
    float mu = s1 * (1.f / 256.f);
    float rs = rsqrtf(fmaxf(s2 * (1.f / 256.f) - mu * mu, 0.f) + LN_EPS);
    xh[tid] = gelu_fast(fmaf((a1 - mu) * rs, pg1[tid], pbe1[tid]));
    __syncthreads();

    // MLP2
    float a2 = pb2[tid];
    #pragma unroll 8
    for (int k = 0; k < 256; ++k)
        a2 = fmaf(xh[k], pw2[(size_t)k * 256 + tid], a2);
    s1 = a2; s2 = a2 * a2;
    s1 = rowsum16(s1); s2 = rowsum16(s2);
    s1 += __shfl_xor(s1, 16); s2 += __shfl_xor(s2, 16);
    s1 += __shfl_xor(s1, 32); s2 += __shfl_xor(s2, 32);
    if ((tid & 63) == 0) { lred[0][wv] = s1; lred[1][wv] = s2; }
    __syncthreads();
    s1 = lred[0][0] + lred[0][1] + lred[0][2] + lred[0][3];
    s2 = lred[1][0] + lred[1][1] + lred[1][2] + lred[1][3];
    mu = s1 * (1.f / 256.f);
    rs = rsqrtf(fmaxf(s2 * (1.f / 256.f) - mu * mu, 0.f) + LN_EPS);
    out[bb * 256 + tid] = fmaf((a2 - mu) * rs, pg2[tid], pbe2[tid]);
}

// ---------------- launch ---------------------------------------------------
extern "C" void kernel_launch(void* const* d_in, const int* in_sizes, int n_in,
                              void* d_out, int out_size, void* d_ws, size_t ws_size,
                              hipStream_t stream)
{
    char* ws = (char*)d_ws;
    unsigned short* w2T      = (unsigned short*)ws;                      // 128 KB
    unsigned short* w1aT     = (unsigned short*)(ws + (128u << 10));     // 32 KB
    unsigned short* w1cT     = (unsigned short*)(ws + (160u << 10));     // 48 KB
    unsigned short* w1bT     = (unsigned short*)(ws + (208u << 10));     // 16 KB
    unsigned int*   pooled_r = (unsigned int*)(ws + (224u << 10));       // 128 KB
    float*          U_p      = (float*)(ws + (512u << 10));              // 16 MB
    float*          V_p      = (float*)(ws + (512u << 10) + (16u << 20)); // 16 MB

    const float* xyz = (const float*)d_in[0];
    const float* pf  = (const float*)d_in[1];
    const float* w1  = (const float*)d_in[2];
    const float* b1  = (const float*)d_in[3];

    k_prep<<<30, 256, 0, stream>>>(w1, (const float*)d_in[6],
                                   w2T, w1aT, w1cT, w1bT, pooled_r);
    k_pre<<<1024, 256, 0, stream>>>(xyz, pf, w1aT, w1cT, b1, U_p, V_p);
    k_main<<<4096, 512, 0, stream>>>(xyz, w1bT, w2T, U_p, V_p,
                                     (const float*)d_in[4], (const float*)d_in[5],
                                     (const float*)d_in[7], (const float*)d_in[8],
                                     (const float*)d_in[9], pooled_r);
    k_final<<<4, 256, 0, stream>>>(pooled_r,
                                   (const float*)d_in[10], (const float*)d_in[11],
                                   (const float*)d_in[12], (const float*)d_in[13],
                                   (const float*)d_in[14], (const float*)d_in[15],
                                   (const float*)d_in[16], (const float*)d_in[17],
                                   (float*)d_out);
}